// Round 11
// baseline (726.543 us; speedup 1.0000x reference)
//
#include <hip/hip_runtime.h>
#include <math.h>

// Problem constants
#define BN 131072
#define KN 1024
#define DN 128
#define GCODES 64
#define NGRP (KN / GCODES)

// epilogue geometry
#define EROWS 64
#define EBLK (BN / EROWS)     // 2048

// fallback geometry
#define ROWS 64
#define NBLK (BN / ROWS)      // 2048

// Ambiguity threshold on approx scores (esq - 2*dot).
#define TAMB 2.5e-4f
// Canary: gross mismatch (e.g. wrong MFMA layout) -> full exact rescan.
#define CANARY 0.01f

typedef __attribute__((ext_vector_type(8))) short s16x8;   // 8 bf16 (4 VGPR)
typedef __attribute__((ext_vector_type(4))) short s16x4;   // 4 bf16 (8B)
typedef __attribute__((ext_vector_type(4))) float f32x4;   // MFMA C/D

__device__ __forceinline__ unsigned short f2bf(float f) {
    const unsigned int u = __float_as_uint(f);
    return (unsigned short)((u + 0x7fffu + ((u >> 16) & 1u)) >> 16);
}
__device__ __forceinline__ float bf2f(unsigned short s) {
    return __uint_as_float(((unsigned int)s) << 16);
}
__device__ __forceinline__ void cvt4(const float4 v, s16x4& h4, s16x4& l4) {
    const unsigned short h0 = f2bf(v.x), h1 = f2bf(v.y), h2 = f2bf(v.z), h3 = f2bf(v.w);
    h4[0] = (short)h0; h4[1] = (short)h1; h4[2] = (short)h2; h4[3] = (short)h3;
    l4[0] = (short)f2bf(v.x - bf2f(h0));
    l4[1] = (short)f2bf(v.y - bf2f(h1));
    l4[2] = (short)f2bf(v.z - bf2f(h2));
    l4[3] = (short)f2bf(v.w - bf2f(h3));
}
__device__ __forceinline__ void cvt8(const float4 v0, const float4 v1,
                                     s16x8& h, s16x8& l) {
    s16x4 h0, l0, h1, l1;
    cvt4(v0, h0, l0); cvt4(v1, h1, l1);
    h[0]=h0[0]; h[1]=h0[1]; h[2]=h0[2]; h[3]=h0[3];
    h[4]=h1[0]; h[5]=h1[1]; h[6]=h1[2]; h[7]=h1[3];
    l[0]=l0[0]; l[1]=l0[1]; l[2]=l0[2]; l[3]=l0[3];
    l[4]=l1[0]; l[5]=l1[1]; l[6]=l1[2]; l[7]=l1[3];
}

// ---------------------------------------------------------------------------
// e_sq[k] = np.sum(codebook[k]^2), numpy pairwise_sum semantics (verified)
// ---------------------------------------------------------------------------
__global__ __launch_bounds__(256) void esq_kernel(const float* __restrict__ cb,
                                                  float* __restrict__ esq) {
    int k = blockIdx.x * 256 + threadIdx.x;
    if (k >= KN) return;
    const float* row = cb + (size_t)k * DN;
    float r[8];
#pragma unroll
    for (int j = 0; j < 8; ++j) r[j] = __fmul_rn(row[j], row[j]);
#pragma unroll
    for (int i = 8; i < DN; i += 8) {
#pragma unroll
        for (int j = 0; j < 8; ++j)
            r[j] = __fadd_rn(r[j], __fmul_rn(row[i + j], row[i + j]));
    }
    esq[k] = __fadd_rn(
        __fadd_rn(__fadd_rn(r[0], r[1]), __fadd_rn(r[2], r[3])),
        __fadd_rn(__fadd_rn(r[4], r[5]), __fadd_rn(r[6], r[7])));
}

// ---------------------------------------------------------------------------
// One-shot codebook conversion -> bf16 hi/lo planes, fragment-linear
// chunk-major per 64-code group.
// ---------------------------------------------------------------------------
__global__ __launch_bounds__(256) void cvt_kernel(const float* __restrict__ cb,
                                                  unsigned short* __restrict__ pl) {
    const int t = blockIdx.x * 256 + threadIdx.x;     // 16384 threads
    const int g = t >> 10, rem = t & 1023;
    const int m = rem >> 6, c = rem & 63;
    const float* src = cb + ((size_t)(g * 64 + c)) * DN + m * 8;
    const float4 v0 = *reinterpret_cast<const float4*>(src);
    const float4 v1 = *reinterpret_cast<const float4*>(src + 4);
    s16x8 h, l;
    cvt8(v0, v1, h, l);
    unsigned short* hb = pl + (size_t)g * 16384 + (m * 64 + c) * 8;
    *reinterpret_cast<s16x8*>(hb)        = h;
    *reinterpret_cast<s16x8*>(hb + 8192) = l;
}

// ---------------------------------------------------------------------------
// z prep: zsq (exact numpy pairwise) + z hi/lo bf16 planes per-16-row tile.
// ---------------------------------------------------------------------------
__global__ __launch_bounds__(256) void zprep_kernel(const float* __restrict__ z,
                                                    unsigned short* __restrict__ zp,
                                                    float* __restrict__ zsq) {
    const int row = blockIdx.x * 256 + threadIdx.x;       // 512 blocks
    const float* zr = z + (size_t)row * DN;
    const int gt = row >> 4, rr = row & 15;
    unsigned short* hb = zp + (size_t)gt * 4096 + rr * 8;
    float a8[8];
#pragma unroll
    for (int m = 0; m < 16; ++m) {
        const float4 v0 = *reinterpret_cast<const float4*>(zr + m * 8);
        const float4 v1 = *reinterpret_cast<const float4*>(zr + m * 8 + 4);
        s16x8 h, l;
        cvt8(v0, v1, h, l);
        *reinterpret_cast<s16x8*>(hb + m * 128)        = h;
        *reinterpret_cast<s16x8*>(hb + 2048 + m * 128) = l;
        if (m == 0) {
            a8[0] = __fmul_rn(v0.x, v0.x); a8[1] = __fmul_rn(v0.y, v0.y);
            a8[2] = __fmul_rn(v0.z, v0.z); a8[3] = __fmul_rn(v0.w, v0.w);
            a8[4] = __fmul_rn(v1.x, v1.x); a8[5] = __fmul_rn(v1.y, v1.y);
            a8[6] = __fmul_rn(v1.z, v1.z); a8[7] = __fmul_rn(v1.w, v1.w);
        } else {
            a8[0] = __fadd_rn(a8[0], __fmul_rn(v0.x, v0.x));
            a8[1] = __fadd_rn(a8[1], __fmul_rn(v0.y, v0.y));
            a8[2] = __fadd_rn(a8[2], __fmul_rn(v0.z, v0.z));
            a8[3] = __fadd_rn(a8[3], __fmul_rn(v0.w, v0.w));
            a8[4] = __fadd_rn(a8[4], __fmul_rn(v1.x, v1.x));
            a8[5] = __fadd_rn(a8[5], __fmul_rn(v1.y, v1.y));
            a8[6] = __fadd_rn(a8[6], __fmul_rn(v1.z, v1.z));
            a8[7] = __fadd_rn(a8[7], __fmul_rn(v1.w, v1.w));
        }
    }
    zsq[row] = __fadd_rn(
        __fadd_rn(__fadd_rn(a8[0], a8[1]), __fadd_rn(a8[2], a8[3])),
        __fadd_rn(__fadd_rn(a8[4], a8[5]), __fadd_rn(a8[6], a8[7])));
}

// ---------------------------------------------------------------------------
// Bit-exact d2 (reference semantics). unroll 4: bounded registers, used only
// on rare paths (canary / fallback tiers).
// ---------------------------------------------------------------------------
__device__ __forceinline__ float exact_d2_g(const float* __restrict__ z,
                                            const float* __restrict__ cb,
                                            const int grow, const int k,
                                            const float zsq, const float ek) {
    const float* zr = z + (size_t)grow * DN;
    const float* cr = cb + (size_t)k * DN;
    float dot = 0.0f;
#pragma unroll 4
    for (int j = 0; j < 32; ++j) {
        const float4 zv = *reinterpret_cast<const float4*>(zr + j * 4);
        const float4 cv = *reinterpret_cast<const float4*>(cr + j * 4);
        dot = __fmaf_rn(zv.x, cv.x, dot);
        dot = __fmaf_rn(zv.y, cv.y, dot);
        dot = __fmaf_rn(zv.z, cv.z, dot);
        dot = __fmaf_rn(zv.w, cv.w, dot);
    }
    return __fadd_rn(__fsub_rn(zsq, __fmul_rn(2.0f, dot)), ek);
}

// ---------------------------------------------------------------------------
// Per-tile MFMA + TOP-2 FIN + partial store. MFMA order/operands identical to
// the validated kernels -> bit-identical scores; B1/B2/I1 values identical to
// the validated top-3 path (B3/I2 simply dropped; finish now full-rescans any
// ambiguous row so they are not needed).
// pquad format: (b1, b2, 0, bits(i1)).
// ---------------------------------------------------------------------------
__device__ __forceinline__ void tile_compute(const s16x8 (&ch)[4][4],
                                             const s16x8 (&cl)[4][4],
                                             const s16x8 (&zh)[4],
                                             const s16x8 (&zl)[4],
                                             const float (&ekv)[16],
                                             const int kbase, const int r0,
                                             float4* __restrict__ pq,
                                             const int l15, const int l4h) {
    f32x4 acc[4];
#pragma unroll
    for (int ct = 0; ct < 4; ++ct) acc[ct] = (f32x4){0.0f, 0.0f, 0.0f, 0.0f};
#pragma unroll
    for (int ks = 0; ks < 4; ++ks) {
#pragma unroll
        for (int ct = 0; ct < 4; ++ct) {
            acc[ct] = __builtin_amdgcn_mfma_f32_16x16x32_bf16(ch[ct][ks], zh[ks], acc[ct], 0, 0, 0);
            acc[ct] = __builtin_amdgcn_mfma_f32_16x16x32_bf16(cl[ct][ks], zh[ks], acc[ct], 0, 0, 0);
            acc[ct] = __builtin_amdgcn_mfma_f32_16x16x32_bf16(ch[ct][ks], zl[ks], acc[ct], 0, 0, 0);
        }
    }
    float b1 = INFINITY, b2 = INFINITY;
    int   i1 = 0;
#pragma unroll
    for (int ct = 0; ct < 4; ++ct) {
#pragma unroll
        for (int e = 0; e < 4; ++e) {
            const float sc = __fmaf_rn(-2.0f, acc[ct][e], ekv[ct * 4 + e]);
            const int   kk = kbase + ct * 16 + l4h * 4 + e;
            const bool lt1 = sc < b1;
            const bool lt2 = sc < b2;
            b2 = lt1 ? b1 : (lt2 ? sc : b2);
            b1 = lt1 ? sc : b1;
            i1 = lt1 ? kk : i1;
        }
    }
#pragma unroll
    for (int st = 16; st < 64; st <<= 1) {
        const float ob1 = __shfl_xor(b1, st);
        const int   oi1 = __shfl_xor(i1, st);
        const float ob2 = __shfl_xor(b2, st);
        if (ob1 < b1) { b2 = fminf(b1, ob2); b1 = ob1; i1 = oi1; }
        else          { b2 = fminf(ob1, b2); }
    }
    if (l4h == 0) {
        float4 q;
        q.x = b1; q.y = b2; q.z = 0.0f;
        q.w = __int_as_float(i1);
        pq[r0 + l15] = q;
    }
}

__device__ __forceinline__ void tile_load_zp(const unsigned short* __restrict__ zb,
                                             s16x8 (&zh)[4], s16x8 (&zl)[4]) {
#pragma unroll
    for (int ks = 0; ks < 4; ++ks) {
        zh[ks] = *reinterpret_cast<const s16x8*>(zb + ks * 512);
        zl[ks] = *reinterpret_cast<const s16x8*>(zb + 2048 + ks * 512);
    }
}

// ===========================================================================
// PHASE 1 (full path): codes-in-registers scorer reading PRE-CONVERTED z.
// Grid 1024 = sliceW*256 + chunk2; 32 row-tiles per block (R10-validated).
// ===========================================================================
__global__ __launch_bounds__(256, 2) void vq_score_pre(const unsigned short* __restrict__ zp,
                                                       const unsigned short* __restrict__ planes,
                                                       const float* __restrict__ esq,
                                                       float4* __restrict__ pquad) {
    const int tid  = threadIdx.x;
    const int lane = tid & 63;
    const int w    = tid >> 6;
    const int l15  = lane & 15;
    const int l4h  = lane >> 4;
    const int sliceW = blockIdx.x >> 8;       // 0..3
    const int chunk2 = blockIdx.x & 255;      // 0..255 (32-tile chunk)
    const int sub    = sliceW * 4 + w;
    const int kbase  = sub * 64;

    s16x8 ch[4][4], cl[4][4];
    {
        const unsigned short* gp = planes + (size_t)sub * 16384;
#pragma unroll
        for (int ks = 0; ks < 4; ++ks)
#pragma unroll
            for (int ct = 0; ct < 4; ++ct) {
                const int off = ((((ks * 4 + l4h) << 6) + (ct << 4) + l15) << 3);
                ch[ct][ks] = *reinterpret_cast<const s16x8*>(gp + off);
                cl[ct][ks] = *reinterpret_cast<const s16x8*>(gp + 8192 + off);
            }
    }
    float ekv[16];
#pragma unroll
    for (int ct = 0; ct < 4; ++ct)
#pragma unroll
        for (int e = 0; e < 4; ++e)
            ekv[ct * 4 + e] = esq[kbase + ct * 16 + l4h * 4 + e];

    const int cbase = chunk2 * 32;
    const int rbase = chunk2 * 512;
    float4* pq = pquad + (size_t)sub * BN;
    const unsigned short* zpl = zp + l4h * 128 + l15 * 8;

    s16x8 hA[4], lA[4], hB[4], lB[4];
    tile_load_zp(zpl + (size_t)cbase * 4096, hA, lA);
#pragma unroll 1
    for (int t = 0; t < 32; t += 2) {
        tile_load_zp(zpl + (size_t)(cbase + t + 1) * 4096, hB, lB);
        tile_compute(ch, cl, hA, lA, ekv, kbase, rbase + t * 16, pq, l15, l4h);
        const int tn = (t + 2 < 32) ? t + 2 : 31;
        tile_load_zp(zpl + (size_t)(cbase + tn) * 4096, hA, lA);
        tile_compute(ch, cl, hB, lB, ekv, kbase, rbase + (t + 1) * 16, pq, l15, l4h);
    }
}

// ===========================================================================
// PHASE 1 (mid path): same scorer with in-kernel z cvt.
// ===========================================================================
__global__ __launch_bounds__(256, 2) void vq_score(const float* __restrict__ z,
                                                   const unsigned short* __restrict__ planes,
                                                   const float* __restrict__ esq,
                                                   float4* __restrict__ pquad) {
    const int tid  = threadIdx.x;
    const int lane = tid & 63;
    const int w    = tid >> 6;
    const int l15  = lane & 15;
    const int l4h  = lane >> 4;
    const int sliceW = blockIdx.x >> 7;
    const int chunk  = blockIdx.x & 127;
    const int sub    = sliceW * 4 + w;
    const int kbase  = sub * 64;

    s16x8 ch[4][4], cl[4][4];
    {
        const unsigned short* gp = planes + (size_t)sub * 16384;
#pragma unroll
        for (int ks = 0; ks < 4; ++ks)
#pragma unroll
            for (int ct = 0; ct < 4; ++ct) {
                const int off = ((((ks * 4 + l4h) << 6) + (ct << 4) + l15) << 3);
                ch[ct][ks] = *reinterpret_cast<const s16x8*>(gp + off);
                cl[ct][ks] = *reinterpret_cast<const s16x8*>(gp + 8192 + off);
            }
    }
    float ekv[16];
#pragma unroll
    for (int ct = 0; ct < 4; ++ct)
#pragma unroll
        for (int e = 0; e < 4; ++e)
            ekv[ct * 4 + e] = esq[kbase + ct * 16 + l4h * 4 + e];

    const int rbase = chunk * 1024;
    float4* pq = pquad + (size_t)sub * BN;

#pragma unroll 1
    for (int t = 0; t < 64; ++t) {
        const int r0 = rbase + t * 16;
        s16x8 zh[4], zl[4];
#pragma unroll
        for (int ks = 0; ks < 4; ++ks) {
            const float* src = z + (size_t)(r0 + l15) * DN + ks * 32 + l4h * 8;
            const float4 v0 = *reinterpret_cast<const float4*>(src);
            const float4 v1 = *reinterpret_cast<const float4*>(src + 4);
            cvt8(v0, v1, zh[ks], zl[ks]);
        }
        tile_compute(ch, cl, zh, zl, ekv, kbase, r0, pq, l15, l4h);
    }
}

// ===========================================================================
// PHASE 2a (merge): 512 blocks x 256 threads, one row per thread, NO LDS,
// NO barriers. 16-way top-2 merge (batched 8+8 loads); writes approx winner
// index for every row; ambiguous rows (B2-B1 <= TAMB, a SUPERSET of the old
// tier2/tier3 sets) appended to a global rescue list; sampled canary
// (1/wave) sets a global flag -> rescue kernel rescans everything.
// ===========================================================================
template <bool HZ>
__global__ __launch_bounds__(256, 2) void vq_merge(const float* __restrict__ z,
                                                   const float* __restrict__ cb,
                                                   const float* __restrict__ esq,
                                                   const float* __restrict__ zsqArr,
                                                   const float4* __restrict__ pquad,
                                                   int* __restrict__ rmeta,
                                                   int* __restrict__ rlist,
                                                   float* __restrict__ out) {
    const int tid = threadIdx.x;
    const int r   = blockIdx.x * 256 + tid;

    float zsq;
    if constexpr (HZ) {
        zsq = zsqArr[r];
    } else {
        const float* zr = z + (size_t)r * DN;
        float a8[8];
#pragma unroll
        for (int c = 0; c < 32; ++c) {
            const float4 v = *reinterpret_cast<const float4*>(zr + c * 4);
            const int t0 = 4 * (c & 1);
            if (c < 2) {
                a8[t0 + 0] = __fmul_rn(v.x, v.x);
                a8[t0 + 1] = __fmul_rn(v.y, v.y);
                a8[t0 + 2] = __fmul_rn(v.z, v.z);
                a8[t0 + 3] = __fmul_rn(v.w, v.w);
            } else {
                a8[t0 + 0] = __fadd_rn(a8[t0 + 0], __fmul_rn(v.x, v.x));
                a8[t0 + 1] = __fadd_rn(a8[t0 + 1], __fmul_rn(v.y, v.y));
                a8[t0 + 2] = __fadd_rn(a8[t0 + 2], __fmul_rn(v.z, v.z));
                a8[t0 + 3] = __fadd_rn(a8[t0 + 3], __fmul_rn(v.w, v.w));
            }
        }
        zsq = __fadd_rn(
            __fadd_rn(__fadd_rn(a8[0], a8[1]), __fadd_rn(a8[2], a8[3])),
            __fadd_rn(__fadd_rn(a8[4], a8[5]), __fadd_rn(a8[6], a8[7])));
    }

    // 16-way top-2 merge (insert order s ascending == ascending code ranges;
    // strict < keeps the lower code -> first-index-of-min semantics)
    float B1 = INFINITY, B2 = INFINITY;
    int   I1 = 0;
#pragma unroll
    for (int half = 0; half < 2; ++half) {
        float4 q[8];
#pragma unroll
        for (int s = 0; s < 8; ++s)
            q[s] = pquad[(size_t)(half * 8 + s) * BN + r];
#pragma unroll
        for (int s = 0; s < 8; ++s) {
            const int j1 = __float_as_int(q[s].w);
            if (q[s].x < B1)      { B2 = B1; B1 = q[s].x; I1 = j1; }
            else if (q[s].x < B2) { B2 = q[s].x; }
            if (q[s].y < B2)      { B2 = q[s].y; }
        }
    }
    out[(size_t)BN * DN + 1 + r] = (float)I1;
    if (B2 - B1 <= TAMB) {
        const int p = atomicAdd(&rmeta[0], 1);
        rlist[p] = r;
    }
    // sampled canary: one row per wave; gross failure is systematic
    if ((tid & 63) == 0) {
        const float d2x  = exact_d2_g(z, cb, r, I1, zsq, esq[I1]);
        const float pred = __fadd_rn(zsq, B1);
        if (fabsf(pred - d2x) > CANARY) atomicExch(&rmeta[1], 1);
    }
}

// ===========================================================================
// PHASE 2b (rescue): one WAVE per flagged row. Exact full 1024-code rescan
// with 16 interleaved per-lane chains (each code's fma chain is the exact
// sequential reference chain; chains for different codes interleave -> ILP 16,
// no dependent-latency serialization). Lexicographic wave reduce (validated).
// If the canary flag is set, rescans ALL rows (catastrophic-correctness path).
// ===========================================================================
template <bool HZ>
__global__ __launch_bounds__(256, 2) void vq_rescue(const float* __restrict__ z,
                                                    const float* __restrict__ cb,
                                                    const float* __restrict__ esq,
                                                    const float* __restrict__ zsqArr,
                                                    const int* __restrict__ rmeta,
                                                    const int* __restrict__ rlist,
                                                    float* __restrict__ out) {
    const int lane = threadIdx.x & 63;
    const int wid  = blockIdx.x * 4 + (threadIdx.x >> 6);
    const int nw   = gridDim.x * 4;
    const int n    = rmeta[0];
    const int flag = rmeta[1];
    const int total = flag ? BN : n;

    for (int ii = wid; ii < total; ii += nw) {
        const int row = flag ? ii : rlist[ii];
        float zsq;
        if constexpr (HZ) {
            zsq = zsqArr[row];
        } else {
            const float* zr0 = z + (size_t)row * DN;
            float a8[8];
#pragma unroll
            for (int c = 0; c < 32; ++c) {
                const float4 v = *reinterpret_cast<const float4*>(zr0 + c * 4);
                const int t0 = 4 * (c & 1);
                if (c < 2) {
                    a8[t0 + 0] = __fmul_rn(v.x, v.x);
                    a8[t0 + 1] = __fmul_rn(v.y, v.y);
                    a8[t0 + 2] = __fmul_rn(v.z, v.z);
                    a8[t0 + 3] = __fmul_rn(v.w, v.w);
                } else {
                    a8[t0 + 0] = __fadd_rn(a8[t0 + 0], __fmul_rn(v.x, v.x));
                    a8[t0 + 1] = __fadd_rn(a8[t0 + 1], __fmul_rn(v.y, v.y));
                    a8[t0 + 2] = __fadd_rn(a8[t0 + 2], __fmul_rn(v.z, v.z));
                    a8[t0 + 3] = __fadd_rn(a8[t0 + 3], __fmul_rn(v.w, v.w));
                }
            }
            zsq = __fadd_rn(
                __fadd_rn(__fadd_rn(a8[0], a8[1]), __fadd_rn(a8[2], a8[3])),
                __fadd_rn(__fadd_rn(a8[4], a8[5]), __fadd_rn(a8[6], a8[7])));
        }

        const float* zr  = z + (size_t)row * DN;
        const float* cbl = cb + (size_t)(lane * 16) * DN;
        float acc[16];
#pragma unroll
        for (int c = 0; c < 16; ++c) acc[c] = 0.0f;
#pragma unroll 1
        for (int j = 0; j < 32; ++j) {
            const float4 z4 = *reinterpret_cast<const float4*>(zr + j * 4);
#pragma unroll
            for (int c = 0; c < 16; ++c) {
                const float4 cv = *reinterpret_cast<const float4*>(
                    cbl + (size_t)c * DN + j * 4);
                float a = acc[c];
                a = __fmaf_rn(z4.x, cv.x, a);
                a = __fmaf_rn(z4.y, cv.y, a);
                a = __fmaf_rn(z4.z, cv.z, a);
                a = __fmaf_rn(z4.w, cv.w, a);
                acc[c] = a;
            }
        }
        // in-lane best (ascending k, strict <), then lexicographic reduce
        float best = INFINITY; int bi = 0;
#pragma unroll
        for (int c = 0; c < 16; ++c) {
            const int k = lane * 16 + c;
            const float d2 = __fadd_rn(__fsub_rn(zsq, __fmul_rn(2.0f, acc[c])),
                                       esq[k]);
            if (d2 < best) { best = d2; bi = k; }
        }
#pragma unroll
        for (int m = 1; m < 64; m <<= 1) {
            const float ob  = __shfl_xor(best, m);
            const int   obi = __shfl_xor(bi, m);
            if (ob < best || (ob == best && obi < bi)) { best = ob; bi = obi; }
        }
        if (lane == 0) out[(size_t)BN * DN + 1 + row] = (float)bi;
    }
}

// ===========================================================================
// PHASE 2c (epilogue): pure streaming (R9-validated). 2048 blocks x 256 thr.
// ===========================================================================
__global__ __launch_bounds__(256, 4) void vq_epilogue(const float* __restrict__ z,
                                                      const float* __restrict__ cb,
                                                      float* __restrict__ out,
                                                      double* __restrict__ partials) {
    __shared__ int sidx[EROWS];
    __shared__ double sls[256];
    const int tid  = threadIdx.x;
    const int row0 = blockIdx.x * EROWS;

    if (tid < EROWS)
        sidx[tid] = (int)out[(size_t)BN * DN + 1 + row0 + tid];
    __syncthreads();

    double ls = 0.0;
    const int j = tid & 31;
#pragma unroll
    for (int half = 0; half < 2; ++half) {
        float4 zb[4], cv[4];
        int rr[4];
#pragma unroll
        for (int u = 0; u < 4; ++u) {
            const int it = half * 4 + u;
            rr[u] = it * 8 + (tid >> 5);
            zb[u] = *reinterpret_cast<const float4*>(
                z + (size_t)(row0 + rr[u]) * DN + j * 4);
            cv[u] = *reinterpret_cast<const float4*>(
                cb + (size_t)sidx[rr[u]] * DN + j * 4);
        }
#pragma unroll
        for (int u = 0; u < 4; ++u) {
            *reinterpret_cast<float4*>(out + (size_t)(row0 + rr[u]) * DN + j * 4) = cv[u];
            const float d0 = __fsub_rn(cv[u].x, zb[u].x);
            const float d1 = __fsub_rn(cv[u].y, zb[u].y);
            const float d2e = __fsub_rn(cv[u].z, zb[u].z);
            const float d3 = __fsub_rn(cv[u].w, zb[u].w);
            ls += (double)__fmul_rn(d0, d0);
            ls += (double)__fmul_rn(d1, d1);
            ls += (double)__fmul_rn(d2e, d2e);
            ls += (double)__fmul_rn(d3, d3);
        }
    }
    sls[tid] = ls;
    __syncthreads();
    for (int s = 128; s > 0; s >>= 1) {
        if (tid < s) sls[tid] += sls[tid + s];
        __syncthreads();
    }
    if (tid == 0) partials[blockIdx.x] = sls[0];
}

#define UPD(s, sc, kk) { \
    const bool lt1 = (sc) < b1v[s]; \
    const bool lt2 = (sc) < b2v[s]; \
    const bool lt3 = (sc) < b3v[s]; \
    b3v[s] = lt2 ? b2v[s] : (lt3 ? (sc) : b3v[s]); \
    b2v[s] = lt1 ? b1v[s] : (lt2 ? (sc) : b2v[s]); \
    i2v[s] = lt1 ? i1v[s] : (lt2 ? (kk) : i2v[s]); \
    b1v[s] = lt1 ? (sc) : b1v[s]; \
    i1v[s] = lt1 ? (kk) : i1v[s]; }

// ---------------------------------------------------------------------------
// Fallback (small workspace): validated R2-structure LDS kernel, in-kernel cvt.
// ---------------------------------------------------------------------------
__global__ __launch_bounds__(256, 2) void vq_lds(const float* __restrict__ z,
                                                 const float* __restrict__ cb,
                                                 const float* __restrict__ esq,
                                                 float* __restrict__ out,
                                                 double* __restrict__ partials) {
    __shared__ __align__(16) short cbS[2][16384];
    __shared__ __align__(16) float sEsq[KN];
    __shared__ float  szsq[ROWS];
    __shared__ float  sB1[2][ROWS], sB2[2][ROWS], sB3[2][ROWS];
    __shared__ int    sI1[2][ROWS], sI2[2][ROWS];
    __shared__ int    sbidx[ROWS];
    __shared__ int    t2list[ROWS], t3list[ROWS];
    __shared__ int    t2n, t3n;
    __shared__ double sls[256];

    const int tid  = threadIdx.x;
    const int lane = tid & 63;
    const int w    = tid >> 6;
    const int l15  = lane & 15;
    const int l4h  = lane >> 4;
    const int wr   = w >> 1;
    const int wc   = w & 1;
    const int row0 = blockIdx.x * ROWS;

    if (tid == 0) { t2n = 0; t3n = 0; }
#pragma unroll
    for (int i = 0; i < 4; ++i) sEsq[i * 256 + tid] = esq[i * 256 + tid];

    float4 stg[8];
#pragma unroll
    for (int i = 0; i < 4; ++i) {
        const int mc = i * 256 + tid, m = mc >> 6, c = mc & 63;
        const float* src = cb + ((size_t)c) * DN + m * 8;
        stg[2 * i]     = *reinterpret_cast<const float4*>(src);
        stg[2 * i + 1] = *reinterpret_cast<const float4*>(src + 4);
    }

    if (tid < ROWS) {
        const float* zr = z + (size_t)(row0 + tid) * DN;
        float rr[8];
#pragma unroll
        for (int c = 0; c < 32; ++c) {
            const float4 v = *reinterpret_cast<const float4*>(zr + c * 4);
            const int t0 = 4 * (c & 1);
            if (c < 2) {
                rr[t0 + 0] = __fmul_rn(v.x, v.x);
                rr[t0 + 1] = __fmul_rn(v.y, v.y);
                rr[t0 + 2] = __fmul_rn(v.z, v.z);
                rr[t0 + 3] = __fmul_rn(v.w, v.w);
            } else {
                rr[t0 + 0] = __fadd_rn(rr[t0 + 0], __fmul_rn(v.x, v.x));
                rr[t0 + 1] = __fadd_rn(rr[t0 + 1], __fmul_rn(v.y, v.y));
                rr[t0 + 2] = __fadd_rn(rr[t0 + 2], __fmul_rn(v.z, v.z));
                rr[t0 + 3] = __fadd_rn(rr[t0 + 3], __fmul_rn(v.w, v.w));
            }
        }
        szsq[tid] = __fadd_rn(
            __fadd_rn(__fadd_rn(rr[0], rr[1]), __fadd_rn(rr[2], rr[3])),
            __fadd_rn(__fadd_rn(rr[4], rr[5]), __fadd_rn(rr[6], rr[7])));
    }

    {
        short* dst = &cbS[0][0];
#pragma unroll
        for (int i = 0; i < 4; ++i) {
            const int mc = i * 256 + tid, m = mc >> 6, c = mc & 63;
            s16x4 h0, l0, h1, l1;
            cvt4(stg[2 * i], h0, l0); cvt4(stg[2 * i + 1], h1, l1);
            short* hb = dst + (m * 64 + c) * 8;
            *reinterpret_cast<s16x4*>(hb)     = h0;
            *reinterpret_cast<s16x4*>(hb + 4) = h1;
            short* lb = hb + 8192;
            *reinterpret_cast<s16x4*>(lb)     = l0;
            *reinterpret_cast<s16x4*>(lb + 4) = l1;
        }
    }

    s16x8 zha[2][4], zla[2][4];
#pragma unroll
    for (int rt = 0; rt < 2; ++rt) {
#pragma unroll
        for (int ks = 0; ks < 4; ++ks) {
            const int rl = row0 + wr * 32 + rt * 16 + l15;
            const float* src = z + (size_t)rl * DN + ks * 32 + l4h * 8;
            const float4 v0 = *reinterpret_cast<const float4*>(src);
            const float4 v1 = *reinterpret_cast<const float4*>(src + 4);
            cvt8(v0, v1, zha[rt][ks], zla[rt][ks]);
        }
    }
    __syncthreads();

    float b1v[8], b2v[8], b3v[8]; int i1v[8], i2v[8];
#pragma unroll
    for (int s = 0; s < 8; ++s) {
        b1v[s] = INFINITY; b2v[s] = INFINITY; b3v[s] = INFINITY;
        i1v[s] = 0; i2v[s] = 0;
    }

    for (int g = 0; g < NGRP; ++g) {
        const int buf = g & 1;
        if (g < NGRP - 1) {
            const int gb = (g + 1) * GCODES;
#pragma unroll
            for (int i = 0; i < 4; ++i) {
                const int mc = i * 256 + tid, m = mc >> 6, c = mc & 63;
                const float* src = cb + ((size_t)(gb + c)) * DN + m * 8;
                stg[2 * i]     = *reinterpret_cast<const float4*>(src);
                stg[2 * i + 1] = *reinterpret_cast<const float4*>(src + 4);
            }
        }

        f32x4 acc[2][2];
#pragma unroll
        for (int rt = 0; rt < 2; ++rt)
#pragma unroll
            for (int ct = 0; ct < 2; ++ct)
                acc[rt][ct] = (f32x4){0.0f, 0.0f, 0.0f, 0.0f};

#pragma unroll
        for (int ks = 0; ks < 4; ++ks) {
            const int b0 = (((ks * 4 + l4h) << 6) + (wc << 5) + l15) << 3;
            const s16x8 bh0 = *reinterpret_cast<const s16x8*>(&cbS[buf][b0]);
            const s16x8 bl0 = *reinterpret_cast<const s16x8*>(&cbS[buf][8192 + b0]);
            const s16x8 bh1 = *reinterpret_cast<const s16x8*>(&cbS[buf][b0 + 128]);
            const s16x8 bl1 = *reinterpret_cast<const s16x8*>(&cbS[buf][8192 + b0 + 128]);
            acc[0][0] = __builtin_amdgcn_mfma_f32_16x16x32_bf16(zha[0][ks], bh0, acc[0][0], 0, 0, 0);
            acc[0][0] = __builtin_amdgcn_mfma_f32_16x16x32_bf16(zla[0][ks], bh0, acc[0][0], 0, 0, 0);
            acc[0][0] = __builtin_amdgcn_mfma_f32_16x16x32_bf16(zha[0][ks], bl0, acc[0][0], 0, 0, 0);
            acc[1][0] = __builtin_amdgcn_mfma_f32_16x16x32_bf16(zha[1][ks], bh0, acc[1][0], 0, 0, 0);
            acc[1][0] = __builtin_amdgcn_mfma_f32_16x16x32_bf16(zla[1][ks], bh0, acc[1][0], 0, 0, 0);
            acc[1][0] = __builtin_amdgcn_mfma_f32_16x16x32_bf16(zha[1][ks], bl0, acc[1][0], 0, 0, 0);
            acc[0][1] = __builtin_amdgcn_mfma_f32_16x16x32_bf16(zha[0][ks], bh1, acc[0][1], 0, 0, 0);
            acc[0][1] = __builtin_amdgcn_mfma_f32_16x16x32_bf16(zla[0][ks], bh1, acc[0][1], 0, 0, 0);
            acc[0][1] = __builtin_amdgcn_mfma_f32_16x16x32_bf16(zha[0][ks], bl1, acc[0][1], 0, 0, 0);
            acc[1][1] = __builtin_amdgcn_mfma_f32_16x16x32_bf16(zha[1][ks], bh1, acc[1][1], 0, 0, 0);
            acc[1][1] = __builtin_amdgcn_mfma_f32_16x16x32_bf16(zla[1][ks], bh1, acc[1][1], 0, 0, 0);
            acc[1][1] = __builtin_amdgcn_mfma_f32_16x16x32_bf16(zha[1][ks], bl1, acc[1][1], 0, 0, 0);
        }

#pragma unroll
        for (int ct = 0; ct < 2; ++ct) {
            const int k = g * GCODES + wc * 32 + ct * 16 + l15;
            const float ek = sEsq[k];
#pragma unroll
            for (int rt = 0; rt < 2; ++rt) {
#pragma unroll
                for (int e = 0; e < 4; ++e) {
                    const float sc = __fmaf_rn(-2.0f, acc[rt][ct][e], ek);
                    UPD(rt * 4 + e, sc, k)
                }
            }
        }

        if (g < NGRP - 1) {
            short* dst = &cbS[buf ^ 1][0];
#pragma unroll
            for (int i = 0; i < 4; ++i) {
                const int mc = i * 256 + tid, m = mc >> 6, c = mc & 63;
                s16x4 h0, l0, h1, l1;
                cvt4(stg[2 * i], h0, l0); cvt4(stg[2 * i + 1], h1, l1);
                short* hb = dst + (m * 64 + c) * 8;
                *reinterpret_cast<s16x4*>(hb)     = h0;
                *reinterpret_cast<s16x4*>(hb + 4) = h1;
                short* lb = hb + 8192;
                *reinterpret_cast<s16x4*>(lb)     = l0;
                *reinterpret_cast<s16x4*>(lb + 4) = l1;
            }
        }
        __syncthreads();
    }

#pragma unroll
    for (int st = 1; st < 16; st <<= 1) {
#pragma unroll
        for (int s = 0; s < 8; ++s) {
            const float ob1 = __shfl_xor(b1v[s], st);
            const int   oi1 = __shfl_xor(i1v[s], st);
            const float ob2 = __shfl_xor(b2v[s], st);
            const int   oi2 = __shfl_xor(i2v[s], st);
            const float ob3 = __shfl_xor(b3v[s], st);
            float v1, v2, v3; int j1, j2;
            if (ob1 < b1v[s]) {
                v1 = ob1; j1 = oi1;
                if (b1v[s] < ob2) { v2 = b1v[s]; j2 = i1v[s]; v3 = fminf(b2v[s], ob2); }
                else              { v2 = ob2;    j2 = oi2;    v3 = fminf(b1v[s], ob3); }
            } else {
                v1 = b1v[s]; j1 = i1v[s];
                if (ob1 < b2v[s]) { v2 = ob1;    j2 = oi1;    v3 = fminf(ob2, b2v[s]); }
                else              { v2 = b2v[s]; j2 = i2v[s]; v3 = fminf(ob1, b3v[s]); }
            }
            b1v[s] = v1; i1v[s] = j1; b2v[s] = v2; i2v[s] = j2; b3v[s] = v3;
        }
    }
    if (l15 == 0) {
#pragma unroll
        for (int s = 0; s < 8; ++s) {
            const int r = wr * 32 + (s >> 2) * 16 + l4h * 4 + (s & 3);
            sB1[wc][r] = b1v[s]; sI1[wc][r] = i1v[s];
            sB2[wc][r] = b2v[s]; sI2[wc][r] = i2v[s];
            sB3[wc][r] = b3v[s];
        }
    }
    __syncthreads();

    if (tid < ROWS) {
        const float a1 = sB1[0][tid]; const int aj1 = sI1[0][tid];
        const float a2 = sB2[0][tid]; const int aj2 = sI2[0][tid];
        const float a3 = sB3[0][tid];
        const float c1 = sB1[1][tid]; const int cj1 = sI1[1][tid];
        const float c2 = sB2[1][tid]; const int cj2 = sI2[1][tid];
        const float c3 = sB3[1][tid];
        float b1, b2, b3; int i1, i2;
        if (a1 <= c1) {
            b1 = a1; i1 = aj1;
            if (a2 <= c1) { b2 = a2; i2 = aj2; b3 = fminf(a3, c1); }
            else          { b2 = c1; i2 = cj1; b3 = fminf(a2, c2); }
        } else {
            b1 = c1; i1 = cj1;
            if (c2 <= a1) { b2 = c2; i2 = cj2; b3 = fminf(c3, a1); }
            else          { b2 = a1; i2 = aj1; b3 = fminf(c2, a2); }
        }
        sbidx[tid] = i1;
        sI1[0][tid] = i1; sI2[0][tid] = i2;
        const float d2x  = exact_d2_g(z, cb, row0 + tid, i1, szsq[tid], sEsq[i1]);
        const float pred = __fadd_rn(szsq[tid], b1);
        const bool bad   = fabsf(pred - d2x) > CANARY;
        if (bad || (b3 - b1 <= TAMB)) {
            const int p = atomicAdd(&t3n, 1); t3list[p] = tid;
        } else if (b2 - b1 <= TAMB) {
            const int p = atomicAdd(&t2n, 1); t2list[p] = tid;
        }
    }
    __syncthreads();

    if (tid < t2n) {
        const int r  = t2list[tid];
        const int ka = sI1[0][r], kb = sI2[0][r];
        const float zsq = szsq[r];
        const float da = exact_d2_g(z, cb, row0 + r, ka, zsq, sEsq[ka]);
        const float db = exact_d2_g(z, cb, row0 + r, kb, zsq, sEsq[kb]);
        int win;
        if (da < db) win = ka;
        else if (db < da) win = kb;
        else win = (ka < kb) ? ka : kb;
        sbidx[r] = win;
    }
    for (int ii = w; ii < t3n; ii += 4) {
        const int r = t3list[ii];
        const float zsq = szsq[r];
        float best = INFINITY; int bi = 0;
#pragma unroll 1
        for (int kk = 0; kk < 16; ++kk) {
            const int k = lane * 16 + kk;
            const float d2v = exact_d2_g(z, cb, row0 + r, k, zsq, sEsq[k]);
            if (d2v < best) { best = d2v; bi = k; }
        }
#pragma unroll
        for (int m = 1; m < 64; m <<= 1) {
            const float ob  = __shfl_xor(best, m);
            const int   obi = __shfl_xor(bi, m);
            if (ob < best || (ob == best && obi < bi)) { best = ob; bi = obi; }
        }
        if (lane == 0) sbidx[r] = bi;
    }
    __syncthreads();

    if (tid < ROWS)
        out[(size_t)BN * DN + 1 + row0 + tid] = (float)sbidx[tid];

    double ls = 0.0;
#pragma unroll
    for (int it = 0; it < 8; ++it) {
        const int r = it * 8 + (tid >> 5);
        const int j = tid & 31;
        const float4 zv = *reinterpret_cast<const float4*>(
            z + ((size_t)(row0 + r)) * DN + j * 4);
        const int bfin = sbidx[r];
        const float4 cv = *reinterpret_cast<const float4*>(
            cb + ((size_t)bfin) * DN + j * 4);
        *reinterpret_cast<float4*>(out + ((size_t)(row0 + r)) * DN + j * 4) = cv;
        const float d0 = __fsub_rn(cv.x, zv.x);
        const float d1 = __fsub_rn(cv.y, zv.y);
        const float d2e = __fsub_rn(cv.z, zv.z);
        const float d3 = __fsub_rn(cv.w, zv.w);
        ls += (double)__fmul_rn(d0, d0);
        ls += (double)__fmul_rn(d1, d1);
        ls += (double)__fmul_rn(d2e, d2e);
        ls += (double)__fmul_rn(d3, d3);
    }
    sls[tid] = ls;
    __syncthreads();
    for (int s = 128; s > 0; s >>= 1) {
        if (tid < s) sls[tid] += sls[tid + s];
        __syncthreads();
    }
    if (tid == 0) partials[blockIdx.x] = sls[0];
}

// ---------------------------------------------------------------------------
// Final loss reduction over n block partials (deterministic)
// ---------------------------------------------------------------------------
__global__ __launch_bounds__(256) void loss_kernel(const double* __restrict__ partials,
                                                   float* __restrict__ out, int n) {
    __shared__ double s[256];
    double acc = 0.0;
    for (int i = threadIdx.x; i < n; i += 256) acc += partials[i];
    s[threadIdx.x] = acc;
    __syncthreads();
    for (int t = 128; t > 0; t >>= 1) {
        if (threadIdx.x < t) s[threadIdx.x] += s[threadIdx.x + t];
        __syncthreads();
    }
    if (threadIdx.x == 0)
        out[(size_t)BN * DN] = (float)(s[0] / ((double)BN * (double)DN));
}

extern "C" void kernel_launch(void* const* d_in, const int* in_sizes, int n_in,
                              void* d_out, int out_size, void* d_ws, size_t ws_size,
                              hipStream_t stream) {
    const float* z  = (const float*)d_in[0];
    const float* cb = (const float*)d_in[1];
    float* out = (float*)d_out;

    // Workspace layout:
    //   [0, 4096)                esq
    //   [4096, 20480)            2048 double partials
    //   [20480, 544768)          cb planes (512KB)
    //   [544768, 34099200)       pquad: 16 x BN x float4 (32MB)
    //   [34099200, 34099328)     rmeta: rcount, gflag
    //   [34099328, 34623616)     rlist (512KB)               == need_mid
    //   [34623616, 35147904)     zsq (512KB)
    //   [35147904, 102256768)    z planes (64MB)             == need_full
    float*          esq      = (float*)d_ws;
    double*         partials = (double*)((char*)d_ws + 4096);
    unsigned short* cbpl     = (unsigned short*)((char*)d_ws + 20480);
    float4*         pquad    = (float4*)((char*)d_ws + 544768);
    int*            rmeta    = (int*)((char*)d_ws + 34099200ull);
    int*            rlist    = (int*)((char*)d_ws + 34099328ull);
    float*          zsqArr   = (float*)((char*)d_ws + 34623616ull);
    unsigned short* zpl      = (unsigned short*)((char*)d_ws + 35147904ull);
    const size_t need_mid  = 34623616ull;
    const size_t need_full = 102256768ull;

    esq_kernel<<<KN / 256, 256, 0, stream>>>(cb, esq);
    if (ws_size >= need_full) {
        cvt_kernel  <<<64, 256, 0, stream>>>(cb, cbpl);
        zprep_kernel<<<BN / 256, 256, 0, stream>>>(z, zpl, zsqArr);
        vq_score_pre<<<1024, 256, 0, stream>>>(zpl, cbpl, esq, pquad);
        hipMemsetAsync(rmeta, 0, 8, stream);
        vq_merge<true> <<<512, 256, 0, stream>>>(z, cb, esq, zsqArr, pquad, rmeta, rlist, out);
        vq_rescue<true><<<512, 256, 0, stream>>>(z, cb, esq, zsqArr, rmeta, rlist, out);
        vq_epilogue <<<EBLK, 256, 0, stream>>>(z, cb, out, partials);
        loss_kernel <<<1, 256, 0, stream>>>(partials, out, EBLK);
    } else if (ws_size >= need_mid) {
        cvt_kernel<<<64, 256, 0, stream>>>(cb, cbpl);
        vq_score  <<<512, 256, 0, stream>>>(z, cbpl, esq, pquad);
        hipMemsetAsync(rmeta, 0, 8, stream);
        vq_merge<false> <<<512, 256, 0, stream>>>(z, cb, esq, nullptr, pquad, rmeta, rlist, out);
        vq_rescue<false><<<512, 256, 0, stream>>>(z, cb, esq, nullptr, rmeta, rlist, out);
        vq_epilogue<<<EBLK, 256, 0, stream>>>(z, cb, out, partials);
        loss_kernel<<<1, 256, 0, stream>>>(partials, out, EBLK);
    } else {
        vq_lds<<<NBLK, 256, 0, stream>>>(z, cb, esq, out, partials);
        loss_kernel<<<1, 256, 0, stream>>>(partials, out, NBLK);
    }
}

// Round 12
// 250.945 us; speedup vs baseline: 2.8952x; 2.8952x over previous
//
#include <hip/hip_runtime.h>
#include <math.h>

// Problem constants
#define BN 131072
#define KN 1024
#define DN 128
#define GCODES 64
#define NGRP (KN / GCODES)

// epilogue geometry
#define EROWS 64
#define EBLK (BN / EROWS)     // 2048

// fallback geometry
#define ROWS 64
#define NBLK (BN / ROWS)      // 2048

// Ambiguity threshold on approx scores (esq - 2*dot).
#define TAMB 2.5e-4f
// Canary: gross mismatch (e.g. wrong MFMA layout) -> full exact rescan.
#define CANARY 0.01f

typedef __attribute__((ext_vector_type(8))) short s16x8;   // 8 bf16 (4 VGPR)
typedef __attribute__((ext_vector_type(4))) short s16x4;   // 4 bf16 (8B)
typedef __attribute__((ext_vector_type(4))) float f32x4;   // MFMA C/D

__device__ __forceinline__ unsigned short f2bf(float f) {
    const unsigned int u = __float_as_uint(f);
    return (unsigned short)((u + 0x7fffu + ((u >> 16) & 1u)) >> 16);
}
__device__ __forceinline__ float bf2f(unsigned short s) {
    return __uint_as_float(((unsigned int)s) << 16);
}
__device__ __forceinline__ void cvt4(const float4 v, s16x4& h4, s16x4& l4) {
    const unsigned short h0 = f2bf(v.x), h1 = f2bf(v.y), h2 = f2bf(v.z), h3 = f2bf(v.w);
    h4[0] = (short)h0; h4[1] = (short)h1; h4[2] = (short)h2; h4[3] = (short)h3;
    l4[0] = (short)f2bf(v.x - bf2f(h0));
    l4[1] = (short)f2bf(v.y - bf2f(h1));
    l4[2] = (short)f2bf(v.z - bf2f(h2));
    l4[3] = (short)f2bf(v.w - bf2f(h3));
}
__device__ __forceinline__ void cvt8(const float4 v0, const float4 v1,
                                     s16x8& h, s16x8& l) {
    s16x4 h0, l0, h1, l1;
    cvt4(v0, h0, l0); cvt4(v1, h1, l1);
    h[0]=h0[0]; h[1]=h0[1]; h[2]=h0[2]; h[3]=h0[3];
    h[4]=h1[0]; h[5]=h1[1]; h[6]=h1[2]; h[7]=h1[3];
    l[0]=l0[0]; l[1]=l0[1]; l[2]=l0[2]; l[3]=l0[3];
    l[4]=l1[0]; l[5]=l1[1]; l[6]=l1[2]; l[7]=l1[3];
}

// ---------------------------------------------------------------------------
// e_sq[k] = np.sum(codebook[k]^2), numpy pairwise_sum semantics (verified)
// ---------------------------------------------------------------------------
__global__ __launch_bounds__(256) void esq_kernel(const float* __restrict__ cb,
                                                  float* __restrict__ esq) {
    int k = blockIdx.x * 256 + threadIdx.x;
    if (k >= KN) return;
    const float* row = cb + (size_t)k * DN;
    float r[8];
#pragma unroll
    for (int j = 0; j < 8; ++j) r[j] = __fmul_rn(row[j], row[j]);
#pragma unroll
    for (int i = 8; i < DN; i += 8) {
#pragma unroll
        for (int j = 0; j < 8; ++j)
            r[j] = __fadd_rn(r[j], __fmul_rn(row[i + j], row[i + j]));
    }
    esq[k] = __fadd_rn(
        __fadd_rn(__fadd_rn(r[0], r[1]), __fadd_rn(r[2], r[3])),
        __fadd_rn(__fadd_rn(r[4], r[5]), __fadd_rn(r[6], r[7])));
}

// ---------------------------------------------------------------------------
// One-shot codebook conversion -> bf16 hi/lo planes, fragment-linear
// chunk-major per 64-code group.
// ---------------------------------------------------------------------------
__global__ __launch_bounds__(256) void cvt_kernel(const float* __restrict__ cb,
                                                  unsigned short* __restrict__ pl) {
    const int t = blockIdx.x * 256 + threadIdx.x;     // 16384 threads
    const int g = t >> 10, rem = t & 1023;
    const int m = rem >> 6, c = rem & 63;
    const float* src = cb + ((size_t)(g * 64 + c)) * DN + m * 8;
    const float4 v0 = *reinterpret_cast<const float4*>(src);
    const float4 v1 = *reinterpret_cast<const float4*>(src + 4);
    s16x8 h, l;
    cvt8(v0, v1, h, l);
    unsigned short* hb = pl + (size_t)g * 16384 + (m * 64 + c) * 8;
    *reinterpret_cast<s16x8*>(hb)        = h;
    *reinterpret_cast<s16x8*>(hb + 8192) = l;
}

// ---------------------------------------------------------------------------
// z prep: zsq (exact numpy pairwise) + z hi/lo bf16 planes per-16-row tile.
// ---------------------------------------------------------------------------
__global__ __launch_bounds__(256) void zprep_kernel(const float* __restrict__ z,
                                                    unsigned short* __restrict__ zp,
                                                    float* __restrict__ zsq) {
    const int row = blockIdx.x * 256 + threadIdx.x;       // 512 blocks
    const float* zr = z + (size_t)row * DN;
    const int gt = row >> 4, rr = row & 15;
    unsigned short* hb = zp + (size_t)gt * 4096 + rr * 8;
    float a8[8];
#pragma unroll
    for (int m = 0; m < 16; ++m) {
        const float4 v0 = *reinterpret_cast<const float4*>(zr + m * 8);
        const float4 v1 = *reinterpret_cast<const float4*>(zr + m * 8 + 4);
        s16x8 h, l;
        cvt8(v0, v1, h, l);
        *reinterpret_cast<s16x8*>(hb + m * 128)        = h;
        *reinterpret_cast<s16x8*>(hb + 2048 + m * 128) = l;
        if (m == 0) {
            a8[0] = __fmul_rn(v0.x, v0.x); a8[1] = __fmul_rn(v0.y, v0.y);
            a8[2] = __fmul_rn(v0.z, v0.z); a8[3] = __fmul_rn(v0.w, v0.w);
            a8[4] = __fmul_rn(v1.x, v1.x); a8[5] = __fmul_rn(v1.y, v1.y);
            a8[6] = __fmul_rn(v1.z, v1.z); a8[7] = __fmul_rn(v1.w, v1.w);
        } else {
            a8[0] = __fadd_rn(a8[0], __fmul_rn(v0.x, v0.x));
            a8[1] = __fadd_rn(a8[1], __fmul_rn(v0.y, v0.y));
            a8[2] = __fadd_rn(a8[2], __fmul_rn(v0.z, v0.z));
            a8[3] = __fadd_rn(a8[3], __fmul_rn(v0.w, v0.w));
            a8[4] = __fadd_rn(a8[4], __fmul_rn(v1.x, v1.x));
            a8[5] = __fadd_rn(a8[5], __fmul_rn(v1.y, v1.y));
            a8[6] = __fadd_rn(a8[6], __fmul_rn(v1.z, v1.z));
            a8[7] = __fadd_rn(a8[7], __fmul_rn(v1.w, v1.w));
        }
    }
    zsq[row] = __fadd_rn(
        __fadd_rn(__fadd_rn(a8[0], a8[1]), __fadd_rn(a8[2], a8[3])),
        __fadd_rn(__fadd_rn(a8[4], a8[5]), __fadd_rn(a8[6], a8[7])));
}

// ---------------------------------------------------------------------------
// Bit-exact d2 (reference semantics): sequential fma chain d=0..127 ascending;
// d2 = fl(fl(zsq - fl(2*dot)) + esq). unroll 4 bounds register pressure.
// ---------------------------------------------------------------------------
__device__ __forceinline__ float exact_d2_g(const float* __restrict__ z,
                                            const float* __restrict__ cb,
                                            const int grow, const int k,
                                            const float zsq, const float ek) {
    const float* zr = z + (size_t)grow * DN;
    const float* cr = cb + (size_t)k * DN;
    float dot = 0.0f;
#pragma unroll 4
    for (int j = 0; j < 32; ++j) {
        const float4 zv = *reinterpret_cast<const float4*>(zr + j * 4);
        const float4 cv = *reinterpret_cast<const float4*>(cr + j * 4);
        dot = __fmaf_rn(zv.x, cv.x, dot);
        dot = __fmaf_rn(zv.y, cv.y, dot);
        dot = __fmaf_rn(zv.z, cv.z, dot);
        dot = __fmaf_rn(zv.w, cv.w, dot);
    }
    return __fadd_rn(__fsub_rn(zsq, __fmul_rn(2.0f, dot)), ek);
}

// ---------------------------------------------------------------------------
// Per-tile MFMA + TOP-3 FIN + partial store (R10-validated numerics, proven).
// pquad format: (b1, b2, b3, bits(i2<<16|i1)).
// ---------------------------------------------------------------------------
__device__ __forceinline__ void tile_compute(const s16x8 (&ch)[4][4],
                                             const s16x8 (&cl)[4][4],
                                             const s16x8 (&zh)[4],
                                             const s16x8 (&zl)[4],
                                             const float (&ekv)[16],
                                             const int kbase, const int r0,
                                             float4* __restrict__ pq,
                                             const int l15, const int l4h) {
    f32x4 acc[4];
#pragma unroll
    for (int ct = 0; ct < 4; ++ct) acc[ct] = (f32x4){0.0f, 0.0f, 0.0f, 0.0f};
#pragma unroll
    for (int ks = 0; ks < 4; ++ks) {
#pragma unroll
        for (int ct = 0; ct < 4; ++ct) {
            acc[ct] = __builtin_amdgcn_mfma_f32_16x16x32_bf16(ch[ct][ks], zh[ks], acc[ct], 0, 0, 0);
            acc[ct] = __builtin_amdgcn_mfma_f32_16x16x32_bf16(cl[ct][ks], zh[ks], acc[ct], 0, 0, 0);
            acc[ct] = __builtin_amdgcn_mfma_f32_16x16x32_bf16(ch[ct][ks], zl[ks], acc[ct], 0, 0, 0);
        }
    }
    float b1 = INFINITY, b2 = INFINITY, b3 = INFINITY;
    int   i1 = 0, i2 = 0;
#pragma unroll
    for (int ct = 0; ct < 4; ++ct) {
#pragma unroll
        for (int e = 0; e < 4; ++e) {
            const float sc = __fmaf_rn(-2.0f, acc[ct][e], ekv[ct * 4 + e]);
            const int   kk = kbase + ct * 16 + l4h * 4 + e;
            const bool lt1 = sc < b1;
            const bool lt2 = sc < b2;
            const bool lt3 = sc < b3;
            b3 = lt2 ? b2 : (lt3 ? sc : b3);
            b2 = lt1 ? b1 : (lt2 ? sc : b2);
            i2 = lt1 ? i1 : (lt2 ? kk : i2);
            b1 = lt1 ? sc : b1;
            i1 = lt1 ? kk : i1;
        }
    }
#pragma unroll
    for (int st = 16; st < 64; st <<= 1) {
        const float ob1 = __shfl_xor(b1, st);
        const int   oi1 = __shfl_xor(i1, st);
        const float ob2 = __shfl_xor(b2, st);
        const int   oi2 = __shfl_xor(i2, st);
        const float ob3 = __shfl_xor(b3, st);
        float v1, v2, v3; int j1, j2;
        if (ob1 < b1) {
            v1 = ob1; j1 = oi1;
            if (b1 < ob2) { v2 = b1;  j2 = i1;  v3 = fminf(b2, ob2); }
            else          { v2 = ob2; j2 = oi2; v3 = fminf(b1, ob3); }
        } else {
            v1 = b1; j1 = i1;
            if (ob1 < b2) { v2 = ob1; j2 = oi1; v3 = fminf(ob2, b2); }
            else          { v2 = b2;  j2 = i2;  v3 = fminf(ob1, b3); }
        }
        b1 = v1; i1 = j1; b2 = v2; i2 = j2; b3 = v3;
    }
    if (l4h == 0) {
        float4 q;
        q.x = b1; q.y = b2; q.z = b3;
        q.w = __int_as_float((i2 << 16) | i1);
        pq[r0 + l15] = q;
    }
}

__device__ __forceinline__ void tile_load_zp(const unsigned short* __restrict__ zb,
                                             s16x8 (&zh)[4], s16x8 (&zl)[4]) {
#pragma unroll
    for (int ks = 0; ks < 4; ++ks) {
        zh[ks] = *reinterpret_cast<const s16x8*>(zb + ks * 512);
        zl[ks] = *reinterpret_cast<const s16x8*>(zb + 2048 + ks * 512);
    }
}

// ===========================================================================
// PHASE 1 (full path, R10-validated): codes-in-registers scorer reading
// PRE-CONVERTED z. Grid 1024 = sliceW*256 + chunk2; 32 row-tiles per block.
// ===========================================================================
__global__ __launch_bounds__(256, 2) void vq_score_pre(const unsigned short* __restrict__ zp,
                                                       const unsigned short* __restrict__ planes,
                                                       const float* __restrict__ esq,
                                                       float4* __restrict__ pquad) {
    const int tid  = threadIdx.x;
    const int lane = tid & 63;
    const int w    = tid >> 6;
    const int l15  = lane & 15;
    const int l4h  = lane >> 4;
    const int sliceW = blockIdx.x >> 8;       // 0..3
    const int chunk2 = blockIdx.x & 255;      // 0..255 (32-tile chunk)
    const int sub    = sliceW * 4 + w;
    const int kbase  = sub * 64;

    s16x8 ch[4][4], cl[4][4];
    {
        const unsigned short* gp = planes + (size_t)sub * 16384;
#pragma unroll
        for (int ks = 0; ks < 4; ++ks)
#pragma unroll
            for (int ct = 0; ct < 4; ++ct) {
                const int off = ((((ks * 4 + l4h) << 6) + (ct << 4) + l15) << 3);
                ch[ct][ks] = *reinterpret_cast<const s16x8*>(gp + off);
                cl[ct][ks] = *reinterpret_cast<const s16x8*>(gp + 8192 + off);
            }
    }
    float ekv[16];
#pragma unroll
    for (int ct = 0; ct < 4; ++ct)
#pragma unroll
        for (int e = 0; e < 4; ++e)
            ekv[ct * 4 + e] = esq[kbase + ct * 16 + l4h * 4 + e];

    const int cbase = chunk2 * 32;
    const int rbase = chunk2 * 512;
    float4* pq = pquad + (size_t)sub * BN;
    const unsigned short* zpl = zp + l4h * 128 + l15 * 8;

    s16x8 hA[4], lA[4], hB[4], lB[4];
    tile_load_zp(zpl + (size_t)cbase * 4096, hA, lA);
#pragma unroll 1
    for (int t = 0; t < 32; t += 2) {
        tile_load_zp(zpl + (size_t)(cbase + t + 1) * 4096, hB, lB);
        tile_compute(ch, cl, hA, lA, ekv, kbase, rbase + t * 16, pq, l15, l4h);
        const int tn = (t + 2 < 32) ? t + 2 : 31;
        tile_load_zp(zpl + (size_t)(cbase + tn) * 4096, hA, lA);
        tile_compute(ch, cl, hB, lB, ekv, kbase, rbase + (t + 1) * 16, pq, l15, l4h);
    }
}

// ===========================================================================
// PHASE 1 (mid path): same scorer with in-kernel z cvt.
// ===========================================================================
__global__ __launch_bounds__(256, 2) void vq_score(const float* __restrict__ z,
                                                   const unsigned short* __restrict__ planes,
                                                   const float* __restrict__ esq,
                                                   float4* __restrict__ pquad) {
    const int tid  = threadIdx.x;
    const int lane = tid & 63;
    const int w    = tid >> 6;
    const int l15  = lane & 15;
    const int l4h  = lane >> 4;
    const int sliceW = blockIdx.x >> 7;
    const int chunk  = blockIdx.x & 127;
    const int sub    = sliceW * 4 + w;
    const int kbase  = sub * 64;

    s16x8 ch[4][4], cl[4][4];
    {
        const unsigned short* gp = planes + (size_t)sub * 16384;
#pragma unroll
        for (int ks = 0; ks < 4; ++ks)
#pragma unroll
            for (int ct = 0; ct < 4; ++ct) {
                const int off = ((((ks * 4 + l4h) << 6) + (ct << 4) + l15) << 3);
                ch[ct][ks] = *reinterpret_cast<const s16x8*>(gp + off);
                cl[ct][ks] = *reinterpret_cast<const s16x8*>(gp + 8192 + off);
            }
    }
    float ekv[16];
#pragma unroll
    for (int ct = 0; ct < 4; ++ct)
#pragma unroll
        for (int e = 0; e < 4; ++e)
            ekv[ct * 4 + e] = esq[kbase + ct * 16 + l4h * 4 + e];

    const int rbase = chunk * 1024;
    float4* pq = pquad + (size_t)sub * BN;

#pragma unroll 1
    for (int t = 0; t < 64; ++t) {
        const int r0 = rbase + t * 16;
        s16x8 zh[4], zl[4];
#pragma unroll
        for (int ks = 0; ks < 4; ++ks) {
            const float* src = z + (size_t)(r0 + l15) * DN + ks * 32 + l4h * 8;
            const float4 v0 = *reinterpret_cast<const float4*>(src);
            const float4 v1 = *reinterpret_cast<const float4*>(src + 4);
            cvt8(v0, v1, zh[ks], zl[ks]);
        }
        tile_compute(ch, cl, zh, zl, ekv, kbase, r0, pq, l15, l4h);
    }
}

// ===========================================================================
// PHASE 2a (merge): 512 blocks x 256 threads, one row per thread, NO LDS,
// NO barriers. 16-way TOP-3 merge (R10-validated sequential insert, batched
// 8+8 loads). Unambiguous -> write I1. Tier-2 (B2-B1<=TAMB<B3-B1) -> inline
// exact rescore of {I1,I2} (2 chains). Tier-3 (B3-B1<=TAMB, rare) -> global
// rescue list. Sampled canary (1/wave) -> global flag (rescue rescans all).
// ===========================================================================
template <bool HZ>
__global__ __launch_bounds__(256, 2) void vq_merge3(const float* __restrict__ z,
                                                    const float* __restrict__ cb,
                                                    const float* __restrict__ esq,
                                                    const float* __restrict__ zsqArr,
                                                    const float4* __restrict__ pquad,
                                                    int* __restrict__ rmeta,
                                                    int* __restrict__ rlist,
                                                    float* __restrict__ out) {
    const int tid = threadIdx.x;
    const int r   = blockIdx.x * 256 + tid;

    float zsq;
    if constexpr (HZ) {
        zsq = zsqArr[r];
    } else {
        const float* zr = z + (size_t)r * DN;
        float a8[8];
#pragma unroll
        for (int c = 0; c < 32; ++c) {
            const float4 v = *reinterpret_cast<const float4*>(zr + c * 4);
            const int t0 = 4 * (c & 1);
            if (c < 2) {
                a8[t0 + 0] = __fmul_rn(v.x, v.x);
                a8[t0 + 1] = __fmul_rn(v.y, v.y);
                a8[t0 + 2] = __fmul_rn(v.z, v.z);
                a8[t0 + 3] = __fmul_rn(v.w, v.w);
            } else {
                a8[t0 + 0] = __fadd_rn(a8[t0 + 0], __fmul_rn(v.x, v.x));
                a8[t0 + 1] = __fadd_rn(a8[t0 + 1], __fmul_rn(v.y, v.y));
                a8[t0 + 2] = __fadd_rn(a8[t0 + 2], __fmul_rn(v.z, v.z));
                a8[t0 + 3] = __fadd_rn(a8[t0 + 3], __fmul_rn(v.w, v.w));
            }
        }
        zsq = __fadd_rn(
            __fadd_rn(__fadd_rn(a8[0], a8[1]), __fadd_rn(a8[2], a8[3])),
            __fadd_rn(__fadd_rn(a8[4], a8[5]), __fadd_rn(a8[6], a8[7])));
    }

    // ---- 16-way top-3 merge (validated insert; s ascending = code order) ---
    float B1 = INFINITY, B2 = INFINITY, B3 = INFINITY;
    int   I1 = 0, I2 = 0;
#pragma unroll
    for (int half = 0; half < 2; ++half) {
        float4 q[8];
#pragma unroll
        for (int s = 0; s < 8; ++s)
            q[s] = pquad[(size_t)(half * 8 + s) * BN + r];
#pragma unroll
        for (int s = 0; s < 8; ++s) {
            const int ii = __float_as_int(q[s].w);
            const int j1 = ii & 0xffff, j2 = ii >> 16;
            if (q[s].x < B1)      { B3 = B2; B2 = B1; I2 = I1; B1 = q[s].x; I1 = j1; }
            else if (q[s].x < B2) { B3 = B2; B2 = q[s].x; I2 = j1; }
            else if (q[s].x < B3) { B3 = q[s].x; }
            if (q[s].y < B2)      { B3 = B2; B2 = q[s].y; I2 = j2; }
            else if (q[s].y < B3) { B3 = q[s].y; }
            B3 = fminf(B3, q[s].z);
        }
    }

    int win = I1;
    if (B3 - B1 <= TAMB) {
        // tier 3 (rare): full exact rescan in the rescue kernel
        const int p = atomicAdd(&rmeta[0], 1);
        rlist[p] = r;
    } else if (B2 - B1 <= TAMB) {
        // tier 2: exact rescore of {I1, I2} (validated chain + tie rule)
        const float da = exact_d2_g(z, cb, r, I1, zsq, esq[I1]);
        const float db = exact_d2_g(z, cb, r, I2, zsq, esq[I2]);
        if (da < db) win = I1;
        else if (db < da) win = I2;
        else win = (I1 < I2) ? I1 : I2;
    }
    out[(size_t)BN * DN + 1 + r] = (float)win;

    // sampled canary: one row per wave; gross failure is systematic
    if ((tid & 63) == 0) {
        const float d2x  = exact_d2_g(z, cb, r, I1, zsq, esq[I1]);
        const float pred = __fadd_rn(zsq, B1);
        if (fabsf(pred - d2x) > CANARY) atomicExch(&rmeta[1], 1);
    }
}

// ===========================================================================
// PHASE 2b (rescue): one WAVE per flagged row (R11-run structure, now rare).
// Exact full 1024-code rescan, 16 interleaved per-lane chains (each chain is
// the exact sequential reference chain). Lexicographic wave reduce.
// If the canary flag is set, rescans ALL rows (catastrophic path).
// ===========================================================================
template <bool HZ>
__global__ __launch_bounds__(256, 2) void vq_rescue(const float* __restrict__ z,
                                                    const float* __restrict__ cb,
                                                    const float* __restrict__ esq,
                                                    const float* __restrict__ zsqArr,
                                                    const int* __restrict__ rmeta,
                                                    const int* __restrict__ rlist,
                                                    float* __restrict__ out) {
    const int lane = threadIdx.x & 63;
    const int wid  = blockIdx.x * 4 + (threadIdx.x >> 6);
    const int nw   = gridDim.x * 4;
    const int n    = rmeta[0];
    const int flag = rmeta[1];
    const int total = flag ? BN : n;

    for (int ii = wid; ii < total; ii += nw) {
        const int row = flag ? ii : rlist[ii];
        float zsq;
        if constexpr (HZ) {
            zsq = zsqArr[row];
        } else {
            const float* zr0 = z + (size_t)row * DN;
            float a8[8];
#pragma unroll
            for (int c = 0; c < 32; ++c) {
                const float4 v = *reinterpret_cast<const float4*>(zr0 + c * 4);
                const int t0 = 4 * (c & 1);
                if (c < 2) {
                    a8[t0 + 0] = __fmul_rn(v.x, v.x);
                    a8[t0 + 1] = __fmul_rn(v.y, v.y);
                    a8[t0 + 2] = __fmul_rn(v.z, v.z);
                    a8[t0 + 3] = __fmul_rn(v.w, v.w);
                } else {
                    a8[t0 + 0] = __fadd_rn(a8[t0 + 0], __fmul_rn(v.x, v.x));
                    a8[t0 + 1] = __fadd_rn(a8[t0 + 1], __fmul_rn(v.y, v.y));
                    a8[t0 + 2] = __fadd_rn(a8[t0 + 2], __fmul_rn(v.z, v.z));
                    a8[t0 + 3] = __fadd_rn(a8[t0 + 3], __fmul_rn(v.w, v.w));
                }
            }
            zsq = __fadd_rn(
                __fadd_rn(__fadd_rn(a8[0], a8[1]), __fadd_rn(a8[2], a8[3])),
                __fadd_rn(__fadd_rn(a8[4], a8[5]), __fadd_rn(a8[6], a8[7])));
        }

        const float* zr  = z + (size_t)row * DN;
        const float* cbl = cb + (size_t)(lane * 16) * DN;
        float acc[16];
#pragma unroll
        for (int c = 0; c < 16; ++c) acc[c] = 0.0f;
#pragma unroll 1
        for (int j = 0; j < 32; ++j) {
            const float4 z4 = *reinterpret_cast<const float4*>(zr + j * 4);
#pragma unroll
            for (int c = 0; c < 16; ++c) {
                const float4 cv = *reinterpret_cast<const float4*>(
                    cbl + (size_t)c * DN + j * 4);
                float a = acc[c];
                a = __fmaf_rn(z4.x, cv.x, a);
                a = __fmaf_rn(z4.y, cv.y, a);
                a = __fmaf_rn(z4.z, cv.z, a);
                a = __fmaf_rn(z4.w, cv.w, a);
                acc[c] = a;
            }
        }
        float best = INFINITY; int bi = 0;
#pragma unroll
        for (int c = 0; c < 16; ++c) {
            const int k = lane * 16 + c;
            const float d2 = __fadd_rn(__fsub_rn(zsq, __fmul_rn(2.0f, acc[c])),
                                       esq[k]);
            if (d2 < best) { best = d2; bi = k; }
        }
#pragma unroll
        for (int m = 1; m < 64; m <<= 1) {
            const float ob  = __shfl_xor(best, m);
            const int   obi = __shfl_xor(bi, m);
            if (ob < best || (ob == best && obi < bi)) { best = ob; bi = obi; }
        }
        if (lane == 0) out[(size_t)BN * DN + 1 + row] = (float)bi;
    }
}

// ===========================================================================
// PHASE 2c (epilogue): pure streaming (R9/R11-run). 2048 blocks x 256 thr.
// ===========================================================================
__global__ __launch_bounds__(256, 4) void vq_epilogue(const float* __restrict__ z,
                                                      const float* __restrict__ cb,
                                                      float* __restrict__ out,
                                                      double* __restrict__ partials) {
    __shared__ int sidx[EROWS];
    __shared__ double sls[256];
    const int tid  = threadIdx.x;
    const int row0 = blockIdx.x * EROWS;

    if (tid < EROWS)
        sidx[tid] = (int)out[(size_t)BN * DN + 1 + row0 + tid];
    __syncthreads();

    double ls = 0.0;
    const int j = tid & 31;
#pragma unroll
    for (int half = 0; half < 2; ++half) {
        float4 zb[4], cv[4];
        int rr[4];
#pragma unroll
        for (int u = 0; u < 4; ++u) {
            const int it = half * 4 + u;
            rr[u] = it * 8 + (tid >> 5);
            zb[u] = *reinterpret_cast<const float4*>(
                z + (size_t)(row0 + rr[u]) * DN + j * 4);
            cv[u] = *reinterpret_cast<const float4*>(
                cb + (size_t)sidx[rr[u]] * DN + j * 4);
        }
#pragma unroll
        for (int u = 0; u < 4; ++u) {
            *reinterpret_cast<float4*>(out + (size_t)(row0 + rr[u]) * DN + j * 4) = cv[u];
            const float d0 = __fsub_rn(cv[u].x, zb[u].x);
            const float d1 = __fsub_rn(cv[u].y, zb[u].y);
            const float d2e = __fsub_rn(cv[u].z, zb[u].z);
            const float d3 = __fsub_rn(cv[u].w, zb[u].w);
            ls += (double)__fmul_rn(d0, d0);
            ls += (double)__fmul_rn(d1, d1);
            ls += (double)__fmul_rn(d2e, d2e);
            ls += (double)__fmul_rn(d3, d3);
        }
    }
    sls[tid] = ls;
    __syncthreads();
    for (int s = 128; s > 0; s >>= 1) {
        if (tid < s) sls[tid] += sls[tid + s];
        __syncthreads();
    }
    if (tid == 0) partials[blockIdx.x] = sls[0];
}

#define UPD(s, sc, kk) { \
    const bool lt1 = (sc) < b1v[s]; \
    const bool lt2 = (sc) < b2v[s]; \
    const bool lt3 = (sc) < b3v[s]; \
    b3v[s] = lt2 ? b2v[s] : (lt3 ? (sc) : b3v[s]); \
    b2v[s] = lt1 ? b1v[s] : (lt2 ? (sc) : b2v[s]); \
    i2v[s] = lt1 ? i1v[s] : (lt2 ? (kk) : i2v[s]); \
    b1v[s] = lt1 ? (sc) : b1v[s]; \
    i1v[s] = lt1 ? (kk) : i1v[s]; }

// ---------------------------------------------------------------------------
// Fallback (small workspace): validated R2-structure LDS kernel, in-kernel cvt.
// ---------------------------------------------------------------------------
__global__ __launch_bounds__(256, 2) void vq_lds(const float* __restrict__ z,
                                                 const float* __restrict__ cb,
                                                 const float* __restrict__ esq,
                                                 float* __restrict__ out,
                                                 double* __restrict__ partials) {
    __shared__ __align__(16) short cbS[2][16384];
    __shared__ __align__(16) float sEsq[KN];
    __shared__ float  szsq[ROWS];
    __shared__ float  sB1[2][ROWS], sB2[2][ROWS], sB3[2][ROWS];
    __shared__ int    sI1[2][ROWS], sI2[2][ROWS];
    __shared__ int    sbidx[ROWS];
    __shared__ int    t2list[ROWS], t3list[ROWS];
    __shared__ int    t2n, t3n;
    __shared__ double sls[256];

    const int tid  = threadIdx.x;
    const int lane = tid & 63;
    const int w    = tid >> 6;
    const int l15  = lane & 15;
    const int l4h  = lane >> 4;
    const int wr   = w >> 1;
    const int wc   = w & 1;
    const int row0 = blockIdx.x * ROWS;

    if (tid == 0) { t2n = 0; t3n = 0; }
#pragma unroll
    for (int i = 0; i < 4; ++i) sEsq[i * 256 + tid] = esq[i * 256 + tid];

    float4 stg[8];
#pragma unroll
    for (int i = 0; i < 4; ++i) {
        const int mc = i * 256 + tid, m = mc >> 6, c = mc & 63;
        const float* src = cb + ((size_t)c) * DN + m * 8;
        stg[2 * i]     = *reinterpret_cast<const float4*>(src);
        stg[2 * i + 1] = *reinterpret_cast<const float4*>(src + 4);
    }

    if (tid < ROWS) {
        const float* zr = z + (size_t)(row0 + tid) * DN;
        float rr[8];
#pragma unroll
        for (int c = 0; c < 32; ++c) {
            const float4 v = *reinterpret_cast<const float4*>(zr + c * 4);
            const int t0 = 4 * (c & 1);
            if (c < 2) {
                rr[t0 + 0] = __fmul_rn(v.x, v.x);
                rr[t0 + 1] = __fmul_rn(v.y, v.y);
                rr[t0 + 2] = __fmul_rn(v.z, v.z);
                rr[t0 + 3] = __fmul_rn(v.w, v.w);
            } else {
                rr[t0 + 0] = __fadd_rn(rr[t0 + 0], __fmul_rn(v.x, v.x));
                rr[t0 + 1] = __fadd_rn(rr[t0 + 1], __fmul_rn(v.y, v.y));
                rr[t0 + 2] = __fadd_rn(rr[t0 + 2], __fmul_rn(v.z, v.z));
                rr[t0 + 3] = __fadd_rn(rr[t0 + 3], __fmul_rn(v.w, v.w));
            }
        }
        szsq[tid] = __fadd_rn(
            __fadd_rn(__fadd_rn(rr[0], rr[1]), __fadd_rn(rr[2], rr[3])),
            __fadd_rn(__fadd_rn(rr[4], rr[5]), __fadd_rn(rr[6], rr[7])));
    }

    {
        short* dst = &cbS[0][0];
#pragma unroll
        for (int i = 0; i < 4; ++i) {
            const int mc = i * 256 + tid, m = mc >> 6, c = mc & 63;
            s16x4 h0, l0, h1, l1;
            cvt4(stg[2 * i], h0, l0); cvt4(stg[2 * i + 1], h1, l1);
            short* hb = dst + (m * 64 + c) * 8;
            *reinterpret_cast<s16x4*>(hb)     = h0;
            *reinterpret_cast<s16x4*>(hb + 4) = h1;
            short* lb = hb + 8192;
            *reinterpret_cast<s16x4*>(lb)     = l0;
            *reinterpret_cast<s16x4*>(lb + 4) = l1;
        }
    }

    s16x8 zha[2][4], zla[2][4];
#pragma unroll
    for (int rt = 0; rt < 2; ++rt) {
#pragma unroll
        for (int ks = 0; ks < 4; ++ks) {
            const int rl = row0 + wr * 32 + rt * 16 + l15;
            const float* src = z + (size_t)rl * DN + ks * 32 + l4h * 8;
            const float4 v0 = *reinterpret_cast<const float4*>(src);
            const float4 v1 = *reinterpret_cast<const float4*>(src + 4);
            cvt8(v0, v1, zha[rt][ks], zla[rt][ks]);
        }
    }
    __syncthreads();

    float b1v[8], b2v[8], b3v[8]; int i1v[8], i2v[8];
#pragma unroll
    for (int s = 0; s < 8; ++s) {
        b1v[s] = INFINITY; b2v[s] = INFINITY; b3v[s] = INFINITY;
        i1v[s] = 0; i2v[s] = 0;
    }

    for (int g = 0; g < NGRP; ++g) {
        const int buf = g & 1;
        if (g < NGRP - 1) {
            const int gb = (g + 1) * GCODES;
#pragma unroll
            for (int i = 0; i < 4; ++i) {
                const int mc = i * 256 + tid, m = mc >> 6, c = mc & 63;
                const float* src = cb + ((size_t)(gb + c)) * DN + m * 8;
                stg[2 * i]     = *reinterpret_cast<const float4*>(src);
                stg[2 * i + 1] = *reinterpret_cast<const float4*>(src + 4);
            }
        }

        f32x4 acc[2][2];
#pragma unroll
        for (int rt = 0; rt < 2; ++rt)
#pragma unroll
            for (int ct = 0; ct < 2; ++ct)
                acc[rt][ct] = (f32x4){0.0f, 0.0f, 0.0f, 0.0f};

#pragma unroll
        for (int ks = 0; ks < 4; ++ks) {
            const int b0 = (((ks * 4 + l4h) << 6) + (wc << 5) + l15) << 3;
            const s16x8 bh0 = *reinterpret_cast<const s16x8*>(&cbS[buf][b0]);
            const s16x8 bl0 = *reinterpret_cast<const s16x8*>(&cbS[buf][8192 + b0]);
            const s16x8 bh1 = *reinterpret_cast<const s16x8*>(&cbS[buf][b0 + 128]);
            const s16x8 bl1 = *reinterpret_cast<const s16x8*>(&cbS[buf][8192 + b0 + 128]);
            acc[0][0] = __builtin_amdgcn_mfma_f32_16x16x32_bf16(zha[0][ks], bh0, acc[0][0], 0, 0, 0);
            acc[0][0] = __builtin_amdgcn_mfma_f32_16x16x32_bf16(zla[0][ks], bh0, acc[0][0], 0, 0, 0);
            acc[0][0] = __builtin_amdgcn_mfma_f32_16x16x32_bf16(zha[0][ks], bl0, acc[0][0], 0, 0, 0);
            acc[1][0] = __builtin_amdgcn_mfma_f32_16x16x32_bf16(zha[1][ks], bh0, acc[1][0], 0, 0, 0);
            acc[1][0] = __builtin_amdgcn_mfma_f32_16x16x32_bf16(zla[1][ks], bh0, acc[1][0], 0, 0, 0);
            acc[1][0] = __builtin_amdgcn_mfma_f32_16x16x32_bf16(zha[1][ks], bl0, acc[1][0], 0, 0, 0);
            acc[0][1] = __builtin_amdgcn_mfma_f32_16x16x32_bf16(zha[0][ks], bh1, acc[0][1], 0, 0, 0);
            acc[0][1] = __builtin_amdgcn_mfma_f32_16x16x32_bf16(zla[0][ks], bh1, acc[0][1], 0, 0, 0);
            acc[0][1] = __builtin_amdgcn_mfma_f32_16x16x32_bf16(zha[0][ks], bl1, acc[0][1], 0, 0, 0);
            acc[1][1] = __builtin_amdgcn_mfma_f32_16x16x32_bf16(zha[1][ks], bh1, acc[1][1], 0, 0, 0);
            acc[1][1] = __builtin_amdgcn_mfma_f32_16x16x32_bf16(zla[1][ks], bh1, acc[1][1], 0, 0, 0);
            acc[1][1] = __builtin_amdgcn_mfma_f32_16x16x32_bf16(zha[1][ks], bl1, acc[1][1], 0, 0, 0);
        }

#pragma unroll
        for (int ct = 0; ct < 2; ++ct) {
            const int k = g * GCODES + wc * 32 + ct * 16 + l15;
            const float ek = sEsq[k];
#pragma unroll
            for (int rt = 0; rt < 2; ++rt) {
#pragma unroll
                for (int e = 0; e < 4; ++e) {
                    const float sc = __fmaf_rn(-2.0f, acc[rt][ct][e], ek);
                    UPD(rt * 4 + e, sc, k)
                }
            }
        }

        if (g < NGRP - 1) {
            short* dst = &cbS[buf ^ 1][0];
#pragma unroll
            for (int i = 0; i < 4; ++i) {
                const int mc = i * 256 + tid, m = mc >> 6, c = mc & 63;
                s16x4 h0, l0, h1, l1;
                cvt4(stg[2 * i], h0, l0); cvt4(stg[2 * i + 1], h1, l1);
                short* hb = dst + (m * 64 + c) * 8;
                *reinterpret_cast<s16x4*>(hb)     = h0;
                *reinterpret_cast<s16x4*>(hb + 4) = h1;
                short* lb = hb + 8192;
                *reinterpret_cast<s16x4*>(lb)     = l0;
                *reinterpret_cast<s16x4*>(lb + 4) = l1;
            }
        }
        __syncthreads();
    }

#pragma unroll
    for (int st = 1; st < 16; st <<= 1) {
#pragma unroll
        for (int s = 0; s < 8; ++s) {
            const float ob1 = __shfl_xor(b1v[s], st);
            const int   oi1 = __shfl_xor(i1v[s], st);
            const float ob2 = __shfl_xor(b2v[s], st);
            const int   oi2 = __shfl_xor(i2v[s], st);
            const float ob3 = __shfl_xor(b3v[s], st);
            float v1, v2, v3; int j1, j2;
            if (ob1 < b1v[s]) {
                v1 = ob1; j1 = oi1;
                if (b1v[s] < ob2) { v2 = b1v[s]; j2 = i1v[s]; v3 = fminf(b2v[s], ob2); }
                else              { v2 = ob2;    j2 = oi2;    v3 = fminf(b1v[s], ob3); }
            } else {
                v1 = b1v[s]; j1 = i1v[s];
                if (ob1 < b2v[s]) { v2 = ob1;    j2 = oi1;    v3 = fminf(ob2, b2v[s]); }
                else              { v2 = b2v[s]; j2 = i2v[s]; v3 = fminf(ob1, b3v[s]); }
            }
            b1v[s] = v1; i1v[s] = j1; b2v[s] = v2; i2v[s] = j2; b3v[s] = v3;
        }
    }
    if (l15 == 0) {
#pragma unroll
        for (int s = 0; s < 8; ++s) {
            const int r = wr * 32 + (s >> 2) * 16 + l4h * 4 + (s & 3);
            sB1[wc][r] = b1v[s]; sI1[wc][r] = i1v[s];
            sB2[wc][r] = b2v[s]; sI2[wc][r] = i2v[s];
            sB3[wc][r] = b3v[s];
        }
    }
    __syncthreads();

    if (tid < ROWS) {
        const float a1 = sB1[0][tid]; const int aj1 = sI1[0][tid];
        const float a2 = sB2[0][tid]; const int aj2 = sI2[0][tid];
        const float a3 = sB3[0][tid];
        const float c1 = sB1[1][tid]; const int cj1 = sI1[1][tid];
        const float c2 = sB2[1][tid]; const int cj2 = sI2[1][tid];
        const float c3 = sB3[1][tid];
        float b1, b2, b3; int i1, i2;
        if (a1 <= c1) {
            b1 = a1; i1 = aj1;
            if (a2 <= c1) { b2 = a2; i2 = aj2; b3 = fminf(a3, c1); }
            else          { b2 = c1; i2 = cj1; b3 = fminf(a2, c2); }
        } else {
            b1 = c1; i1 = cj1;
            if (c2 <= a1) { b2 = c2; i2 = cj2; b3 = fminf(c3, a1); }
            else          { b2 = a1; i2 = aj1; b3 = fminf(c2, a2); }
        }
        sbidx[tid] = i1;
        sI1[0][tid] = i1; sI2[0][tid] = i2;
        const float d2x  = exact_d2_g(z, cb, row0 + tid, i1, szsq[tid], sEsq[i1]);
        const float pred = __fadd_rn(szsq[tid], b1);
        const bool bad   = fabsf(pred - d2x) > CANARY;
        if (bad || (b3 - b1 <= TAMB)) {
            const int p = atomicAdd(&t3n, 1); t3list[p] = tid;
        } else if (b2 - b1 <= TAMB) {
            const int p = atomicAdd(&t2n, 1); t2list[p] = tid;
        }
    }
    __syncthreads();

    if (tid < t2n) {
        const int r  = t2list[tid];
        const int ka = sI1[0][r], kb = sI2[0][r];
        const float zsq = szsq[r];
        const float da = exact_d2_g(z, cb, row0 + r, ka, zsq, sEsq[ka]);
        const float db = exact_d2_g(z, cb, row0 + r, kb, zsq, sEsq[kb]);
        int win;
        if (da < db) win = ka;
        else if (db < da) win = kb;
        else win = (ka < kb) ? ka : kb;
        sbidx[r] = win;
    }
    for (int ii = w; ii < t3n; ii += 4) {
        const int r = t3list[ii];
        const float zsq = szsq[r];
        float best = INFINITY; int bi = 0;
#pragma unroll 1
        for (int kk = 0; kk < 16; ++kk) {
            const int k = lane * 16 + kk;
            const float d2v = exact_d2_g(z, cb, row0 + r, k, zsq, sEsq[k]);
            if (d2v < best) { best = d2v; bi = k; }
        }
#pragma unroll
        for (int m = 1; m < 64; m <<= 1) {
            const float ob  = __shfl_xor(best, m);
            const int   obi = __shfl_xor(bi, m);
            if (ob < best || (ob == best && obi < bi)) { best = ob; bi = obi; }
        }
        if (lane == 0) sbidx[r] = bi;
    }
    __syncthreads();

    if (tid < ROWS)
        out[(size_t)BN * DN + 1 + row0 + tid] = (float)sbidx[tid];

    double ls = 0.0;
#pragma unroll
    for (int it = 0; it < 8; ++it) {
        const int r = it * 8 + (tid >> 5);
        const int j = tid & 31;
        const float4 zv = *reinterpret_cast<const float4*>(
            z + ((size_t)(row0 + r)) * DN + j * 4);
        const int bfin = sbidx[r];
        const float4 cv = *reinterpret_cast<const float4*>(
            cb + ((size_t)bfin) * DN + j * 4);
        *reinterpret_cast<float4*>(out + ((size_t)(row0 + r)) * DN + j * 4) = cv;
        const float d0 = __fsub_rn(cv.x, zv.x);
        const float d1 = __fsub_rn(cv.y, zv.y);
        const float d2e = __fsub_rn(cv.z, zv.z);
        const float d3 = __fsub_rn(cv.w, zv.w);
        ls += (double)__fmul_rn(d0, d0);
        ls += (double)__fmul_rn(d1, d1);
        ls += (double)__fmul_rn(d2e, d2e);
        ls += (double)__fmul_rn(d3, d3);
    }
    sls[tid] = ls;
    __syncthreads();
    for (int s = 128; s > 0; s >>= 1) {
        if (tid < s) sls[tid] += sls[tid + s];
        __syncthreads();
    }
    if (tid == 0) partials[blockIdx.x] = sls[0];
}

// ---------------------------------------------------------------------------
// Final loss reduction over n block partials (deterministic)
// ---------------------------------------------------------------------------
__global__ __launch_bounds__(256) void loss_kernel(const double* __restrict__ partials,
                                                   float* __restrict__ out, int n) {
    __shared__ double s[256];
    double acc = 0.0;
    for (int i = threadIdx.x; i < n; i += 256) acc += partials[i];
    s[threadIdx.x] = acc;
    __syncthreads();
    for (int t = 128; t > 0; t >>= 1) {
        if (threadIdx.x < t) s[threadIdx.x] += s[threadIdx.x + t];
        __syncthreads();
    }
    if (threadIdx.x == 0)
        out[(size_t)BN * DN] = (float)(s[0] / ((double)BN * (double)DN));
}

extern "C" void kernel_launch(void* const* d_in, const int* in_sizes, int n_in,
                              void* d_out, int out_size, void* d_ws, size_t ws_size,
                              hipStream_t stream) {
    const float* z  = (const float*)d_in[0];
    const float* cb = (const float*)d_in[1];
    float* out = (float*)d_out;

    // Workspace layout:
    //   [0, 4096)                esq
    //   [4096, 20480)            2048 double partials
    //   [20480, 544768)          cb planes (512KB)
    //   [544768, 34099200)       pquad: 16 x BN x float4 (32MB)
    //   [34099200, 34099328)     rmeta: rcount, gflag
    //   [34099328, 34623616)     rlist (512KB)               == need_mid
    //   [34623616, 35147904)     zsq (512KB)
    //   [35147904, 102256768)    z planes (64MB)             == need_full
    float*          esq      = (float*)d_ws;
    double*         partials = (double*)((char*)d_ws + 4096);
    unsigned short* cbpl     = (unsigned short*)((char*)d_ws + 20480);
    float4*         pquad    = (float4*)((char*)d_ws + 544768);
    int*            rmeta    = (int*)((char*)d_ws + 34099200ull);
    int*            rlist    = (int*)((char*)d_ws + 34099328ull);
    float*          zsqArr   = (float*)((char*)d_ws + 34623616ull);
    unsigned short* zpl      = (unsigned short*)((char*)d_ws + 35147904ull);
    const size_t need_mid  = 34623616ull;
    const size_t need_full = 102256768ull;

    esq_kernel<<<KN / 256, 256, 0, stream>>>(cb, esq);
    if (ws_size >= need_full) {
        cvt_kernel  <<<64, 256, 0, stream>>>(cb, cbpl);
        zprep_kernel<<<BN / 256, 256, 0, stream>>>(z, zpl, zsqArr);
        vq_score_pre<<<1024, 256, 0, stream>>>(zpl, cbpl, esq, pquad);
        hipMemsetAsync(rmeta, 0, 8, stream);
        vq_merge3<true> <<<512, 256, 0, stream>>>(z, cb, esq, zsqArr, pquad, rmeta, rlist, out);
        vq_rescue<true> <<<512, 256, 0, stream>>>(z, cb, esq, zsqArr, rmeta, rlist, out);
        vq_epilogue <<<EBLK, 256, 0, stream>>>(z, cb, out, partials);
        loss_kernel <<<1, 256, 0, stream>>>(partials, out, EBLK);
    } else if (ws_size >= need_mid) {
        cvt_kernel<<<64, 256, 0, stream>>>(cb, cbpl);
        vq_score  <<<512, 256, 0, stream>>>(z, cbpl, esq, pquad);
        hipMemsetAsync(rmeta, 0, 8, stream);
        vq_merge3<false> <<<512, 256, 0, stream>>>(z, cb, esq, nullptr, pquad, rmeta, rlist, out);
        vq_rescue<false> <<<512, 256, 0, stream>>>(z, cb, esq, nullptr, rmeta, rlist, out);
        vq_epilogue<<<EBLK, 256, 0, stream>>>(z, cb, out, partials);
        loss_kernel<<<1, 256, 0, stream>>>(partials, out, EBLK);
    } else {
        vq_lds<<<NBLK, 256, 0, stream>>>(z, cb, esq, out, partials);
        loss_kernel<<<1, 256, 0, stream>>>(partials, out, NBLK);
    }
}

// Round 13
// 231.337 us; speedup vs baseline: 3.1406x; 1.0848x over previous
//
#include <hip/hip_runtime.h>
#include <math.h>

// Problem constants
#define BN 131072
#define KN 1024
#define DN 128
#define GCODES 64
#define NGRP (KN / GCODES)

// epilogue geometry
#define EROWS 64
#define EBLK (BN / EROWS)     // 2048

// fallback geometry
#define ROWS 64
#define NBLK (BN / ROWS)      // 2048

// Ambiguity threshold on approx scores (esq - 2*dot).
#define TAMB 2.5e-4f
// Canary: gross mismatch (e.g. wrong MFMA layout) -> full exact rescan.
#define CANARY 0.01f

typedef __attribute__((ext_vector_type(8))) short s16x8;   // 8 bf16 (4 VGPR)
typedef __attribute__((ext_vector_type(4))) short s16x4;   // 4 bf16 (8B)
typedef __attribute__((ext_vector_type(4))) float f32x4;   // MFMA C/D

__device__ __forceinline__ unsigned short f2bf(float f) {
    const unsigned int u = __float_as_uint(f);
    return (unsigned short)((u + 0x7fffu + ((u >> 16) & 1u)) >> 16);
}
__device__ __forceinline__ float bf2f(unsigned short s) {
    return __uint_as_float(((unsigned int)s) << 16);
}
__device__ __forceinline__ void cvt4(const float4 v, s16x4& h4, s16x4& l4) {
    const unsigned short h0 = f2bf(v.x), h1 = f2bf(v.y), h2 = f2bf(v.z), h3 = f2bf(v.w);
    h4[0] = (short)h0; h4[1] = (short)h1; h4[2] = (short)h2; h4[3] = (short)h3;
    l4[0] = (short)f2bf(v.x - bf2f(h0));
    l4[1] = (short)f2bf(v.y - bf2f(h1));
    l4[2] = (short)f2bf(v.z - bf2f(h2));
    l4[3] = (short)f2bf(v.w - bf2f(h3));
}
__device__ __forceinline__ void cvt8(const float4 v0, const float4 v1,
                                     s16x8& h, s16x8& l) {
    s16x4 h0, l0, h1, l1;
    cvt4(v0, h0, l0); cvt4(v1, h1, l1);
    h[0]=h0[0]; h[1]=h0[1]; h[2]=h0[2]; h[3]=h0[3];
    h[4]=h1[0]; h[5]=h1[1]; h[6]=h1[2]; h[7]=h1[3];
    l[0]=l0[0]; l[1]=l0[1]; l[2]=l0[2]; l[3]=l0[3];
    l[4]=l1[0]; l[5]=l1[1]; l[6]=l1[2]; l[7]=l1[3];
}

// ---------------------------------------------------------------------------
// e_sq[k] = np.sum(codebook[k]^2), numpy pairwise_sum semantics (verified)
// ---------------------------------------------------------------------------
__global__ __launch_bounds__(256) void esq_kernel(const float* __restrict__ cb,
                                                  float* __restrict__ esq) {
    int k = blockIdx.x * 256 + threadIdx.x;
    if (k >= KN) return;
    const float* row = cb + (size_t)k * DN;
    float r[8];
#pragma unroll
    for (int j = 0; j < 8; ++j) r[j] = __fmul_rn(row[j], row[j]);
#pragma unroll
    for (int i = 8; i < DN; i += 8) {
#pragma unroll
        for (int j = 0; j < 8; ++j)
            r[j] = __fadd_rn(r[j], __fmul_rn(row[i + j], row[i + j]));
    }
    esq[k] = __fadd_rn(
        __fadd_rn(__fadd_rn(r[0], r[1]), __fadd_rn(r[2], r[3])),
        __fadd_rn(__fadd_rn(r[4], r[5]), __fadd_rn(r[6], r[7])));
}

// ---------------------------------------------------------------------------
// One-shot codebook conversion -> bf16 hi/lo planes, fragment-linear
// chunk-major per 64-code group.
// ---------------------------------------------------------------------------
__global__ __launch_bounds__(256) void cvt_kernel(const float* __restrict__ cb,
                                                  unsigned short* __restrict__ pl) {
    const int t = blockIdx.x * 256 + threadIdx.x;     // 16384 threads
    const int g = t >> 10, rem = t & 1023;
    const int m = rem >> 6, c = rem & 63;
    const float* src = cb + ((size_t)(g * 64 + c)) * DN + m * 8;
    const float4 v0 = *reinterpret_cast<const float4*>(src);
    const float4 v1 = *reinterpret_cast<const float4*>(src + 4);
    s16x8 h, l;
    cvt8(v0, v1, h, l);
    unsigned short* hb = pl + (size_t)g * 16384 + (m * 64 + c) * 8;
    *reinterpret_cast<s16x8*>(hb)        = h;
    *reinterpret_cast<s16x8*>(hb + 8192) = l;
}

// ---------------------------------------------------------------------------
// One-shot fp32 codebook transpose: cbT[d*KN + k] = cb[k*DN + d].
// Enables fully-coalesced exact rescans (rescue kernel).
// ---------------------------------------------------------------------------
__global__ __launch_bounds__(256) void cvtT_kernel(const float* __restrict__ cb,
                                                   float* __restrict__ cbT) {
    const int idx = blockIdx.x * 256 + threadIdx.x;   // 131072 threads
    const int d = idx >> 10, k = idx & 1023;
    cbT[idx] = cb[(size_t)k * DN + d];
}

// ---------------------------------------------------------------------------
// z prep: zsq (exact numpy pairwise) + z hi/lo bf16 planes per-16-row tile.
// ---------------------------------------------------------------------------
__global__ __launch_bounds__(256) void zprep_kernel(const float* __restrict__ z,
                                                    unsigned short* __restrict__ zp,
                                                    float* __restrict__ zsq) {
    const int row = blockIdx.x * 256 + threadIdx.x;       // 512 blocks
    const float* zr = z + (size_t)row * DN;
    const int gt = row >> 4, rr = row & 15;
    unsigned short* hb = zp + (size_t)gt * 4096 + rr * 8;
    float a8[8];
#pragma unroll
    for (int m = 0; m < 16; ++m) {
        const float4 v0 = *reinterpret_cast<const float4*>(zr + m * 8);
        const float4 v1 = *reinterpret_cast<const float4*>(zr + m * 8 + 4);
        s16x8 h, l;
        cvt8(v0, v1, h, l);
        *reinterpret_cast<s16x8*>(hb + m * 128)        = h;
        *reinterpret_cast<s16x8*>(hb + 2048 + m * 128) = l;
        if (m == 0) {
            a8[0] = __fmul_rn(v0.x, v0.x); a8[1] = __fmul_rn(v0.y, v0.y);
            a8[2] = __fmul_rn(v0.z, v0.z); a8[3] = __fmul_rn(v0.w, v0.w);
            a8[4] = __fmul_rn(v1.x, v1.x); a8[5] = __fmul_rn(v1.y, v1.y);
            a8[6] = __fmul_rn(v1.z, v1.z); a8[7] = __fmul_rn(v1.w, v1.w);
        } else {
            a8[0] = __fadd_rn(a8[0], __fmul_rn(v0.x, v0.x));
            a8[1] = __fadd_rn(a8[1], __fmul_rn(v0.y, v0.y));
            a8[2] = __fadd_rn(a8[2], __fmul_rn(v0.z, v0.z));
            a8[3] = __fadd_rn(a8[3], __fmul_rn(v0.w, v0.w));
            a8[4] = __fadd_rn(a8[4], __fmul_rn(v1.x, v1.x));
            a8[5] = __fadd_rn(a8[5], __fmul_rn(v1.y, v1.y));
            a8[6] = __fadd_rn(a8[6], __fmul_rn(v1.z, v1.z));
            a8[7] = __fadd_rn(a8[7], __fmul_rn(v1.w, v1.w));
        }
    }
    zsq[row] = __fadd_rn(
        __fadd_rn(__fadd_rn(a8[0], a8[1]), __fadd_rn(a8[2], a8[3])),
        __fadd_rn(__fadd_rn(a8[4], a8[5]), __fadd_rn(a8[6], a8[7])));
}

// ---------------------------------------------------------------------------
// Bit-exact d2 (reference semantics): sequential fma chain d=0..127 ascending;
// d2 = fl(fl(zsq - fl(2*dot)) + esq). unroll 4 bounds register pressure.
// ---------------------------------------------------------------------------
__device__ __forceinline__ float exact_d2_g(const float* __restrict__ z,
                                            const float* __restrict__ cb,
                                            const int grow, const int k,
                                            const float zsq, const float ek) {
    const float* zr = z + (size_t)grow * DN;
    const float* cr = cb + (size_t)k * DN;
    float dot = 0.0f;
#pragma unroll 4
    for (int j = 0; j < 32; ++j) {
        const float4 zv = *reinterpret_cast<const float4*>(zr + j * 4);
        const float4 cv = *reinterpret_cast<const float4*>(cr + j * 4);
        dot = __fmaf_rn(zv.x, cv.x, dot);
        dot = __fmaf_rn(zv.y, cv.y, dot);
        dot = __fmaf_rn(zv.z, cv.z, dot);
        dot = __fmaf_rn(zv.w, cv.w, dot);
    }
    return __fadd_rn(__fsub_rn(zsq, __fmul_rn(2.0f, dot)), ek);
}

// ---------------------------------------------------------------------------
// Per-tile MFMA + TOP-3 FIN + partial store (R10-validated numerics, proven).
// pquad format: (b1, b2, b3, bits(i2<<16|i1)).
// ---------------------------------------------------------------------------
__device__ __forceinline__ void tile_compute(const s16x8 (&ch)[4][4],
                                             const s16x8 (&cl)[4][4],
                                             const s16x8 (&zh)[4],
                                             const s16x8 (&zl)[4],
                                             const float (&ekv)[16],
                                             const int kbase, const int r0,
                                             float4* __restrict__ pq,
                                             const int l15, const int l4h) {
    f32x4 acc[4];
#pragma unroll
    for (int ct = 0; ct < 4; ++ct) acc[ct] = (f32x4){0.0f, 0.0f, 0.0f, 0.0f};
#pragma unroll
    for (int ks = 0; ks < 4; ++ks) {
#pragma unroll
        for (int ct = 0; ct < 4; ++ct) {
            acc[ct] = __builtin_amdgcn_mfma_f32_16x16x32_bf16(ch[ct][ks], zh[ks], acc[ct], 0, 0, 0);
            acc[ct] = __builtin_amdgcn_mfma_f32_16x16x32_bf16(cl[ct][ks], zh[ks], acc[ct], 0, 0, 0);
            acc[ct] = __builtin_amdgcn_mfma_f32_16x16x32_bf16(ch[ct][ks], zl[ks], acc[ct], 0, 0, 0);
        }
    }
    float b1 = INFINITY, b2 = INFINITY, b3 = INFINITY;
    int   i1 = 0, i2 = 0;
#pragma unroll
    for (int ct = 0; ct < 4; ++ct) {
#pragma unroll
        for (int e = 0; e < 4; ++e) {
            const float sc = __fmaf_rn(-2.0f, acc[ct][e], ekv[ct * 4 + e]);
            const int   kk = kbase + ct * 16 + l4h * 4 + e;
            const bool lt1 = sc < b1;
            const bool lt2 = sc < b2;
            const bool lt3 = sc < b3;
            b3 = lt2 ? b2 : (lt3 ? sc : b3);
            b2 = lt1 ? b1 : (lt2 ? sc : b2);
            i2 = lt1 ? i1 : (lt2 ? kk : i2);
            b1 = lt1 ? sc : b1;
            i1 = lt1 ? kk : i1;
        }
    }
#pragma unroll
    for (int st = 16; st < 64; st <<= 1) {
        const float ob1 = __shfl_xor(b1, st);
        const int   oi1 = __shfl_xor(i1, st);
        const float ob2 = __shfl_xor(b2, st);
        const int   oi2 = __shfl_xor(i2, st);
        const float ob3 = __shfl_xor(b3, st);
        float v1, v2, v3; int j1, j2;
        if (ob1 < b1) {
            v1 = ob1; j1 = oi1;
            if (b1 < ob2) { v2 = b1;  j2 = i1;  v3 = fminf(b2, ob2); }
            else          { v2 = ob2; j2 = oi2; v3 = fminf(b1, ob3); }
        } else {
            v1 = b1; j1 = i1;
            if (ob1 < b2) { v2 = ob1; j2 = oi1; v3 = fminf(ob2, b2); }
            else          { v2 = b2;  j2 = i2;  v3 = fminf(ob1, b3); }
        }
        b1 = v1; i1 = j1; b2 = v2; i2 = j2; b3 = v3;
    }
    if (l4h == 0) {
        float4 q;
        q.x = b1; q.y = b2; q.z = b3;
        q.w = __int_as_float((i2 << 16) | i1);
        pq[r0 + l15] = q;
    }
}

__device__ __forceinline__ void tile_load_zp(const unsigned short* __restrict__ zb,
                                             s16x8 (&zh)[4], s16x8 (&zl)[4]) {
#pragma unroll
    for (int ks = 0; ks < 4; ++ks) {
        zh[ks] = *reinterpret_cast<const s16x8*>(zb + ks * 512);
        zl[ks] = *reinterpret_cast<const s16x8*>(zb + 2048 + ks * 512);
    }
}

// ===========================================================================
// PHASE 1 (full path, R10-validated): codes-in-registers scorer reading
// PRE-CONVERTED z. Grid 1024 = sliceW*256 + chunk2; 32 row-tiles per block.
// ===========================================================================
__global__ __launch_bounds__(256, 2) void vq_score_pre(const unsigned short* __restrict__ zp,
                                                       const unsigned short* __restrict__ planes,
                                                       const float* __restrict__ esq,
                                                       float4* __restrict__ pquad) {
    const int tid  = threadIdx.x;
    const int lane = tid & 63;
    const int w    = tid >> 6;
    const int l15  = lane & 15;
    const int l4h  = lane >> 4;
    const int sliceW = blockIdx.x >> 8;       // 0..3
    const int chunk2 = blockIdx.x & 255;      // 0..255 (32-tile chunk)
    const int sub    = sliceW * 4 + w;
    const int kbase  = sub * 64;

    s16x8 ch[4][4], cl[4][4];
    {
        const unsigned short* gp = planes + (size_t)sub * 16384;
#pragma unroll
        for (int ks = 0; ks < 4; ++ks)
#pragma unroll
            for (int ct = 0; ct < 4; ++ct) {
                const int off = ((((ks * 4 + l4h) << 6) + (ct << 4) + l15) << 3);
                ch[ct][ks] = *reinterpret_cast<const s16x8*>(gp + off);
                cl[ct][ks] = *reinterpret_cast<const s16x8*>(gp + 8192 + off);
            }
    }
    float ekv[16];
#pragma unroll
    for (int ct = 0; ct < 4; ++ct)
#pragma unroll
        for (int e = 0; e < 4; ++e)
            ekv[ct * 4 + e] = esq[kbase + ct * 16 + l4h * 4 + e];

    const int cbase = chunk2 * 32;
    const int rbase = chunk2 * 512;
    float4* pq = pquad + (size_t)sub * BN;
    const unsigned short* zpl = zp + l4h * 128 + l15 * 8;

    s16x8 hA[4], lA[4], hB[4], lB[4];
    tile_load_zp(zpl + (size_t)cbase * 4096, hA, lA);
#pragma unroll 1
    for (int t = 0; t < 32; t += 2) {
        tile_load_zp(zpl + (size_t)(cbase + t + 1) * 4096, hB, lB);
        tile_compute(ch, cl, hA, lA, ekv, kbase, rbase + t * 16, pq, l15, l4h);
        const int tn = (t + 2 < 32) ? t + 2 : 31;
        tile_load_zp(zpl + (size_t)(cbase + tn) * 4096, hA, lA);
        tile_compute(ch, cl, hB, lB, ekv, kbase, rbase + (t + 1) * 16, pq, l15, l4h);
    }
}

// ===========================================================================
// PHASE 1 (mid path): same scorer with in-kernel z cvt.
// ===========================================================================
__global__ __launch_bounds__(256, 2) void vq_score(const float* __restrict__ z,
                                                   const unsigned short* __restrict__ planes,
                                                   const float* __restrict__ esq,
                                                   float4* __restrict__ pquad) {
    const int tid  = threadIdx.x;
    const int lane = tid & 63;
    const int w    = tid >> 6;
    const int l15  = lane & 15;
    const int l4h  = lane >> 4;
    const int sliceW = blockIdx.x >> 7;
    const int chunk  = blockIdx.x & 127;
    const int sub    = sliceW * 4 + w;
    const int kbase  = sub * 64;

    s16x8 ch[4][4], cl[4][4];
    {
        const unsigned short* gp = planes + (size_t)sub * 16384;
#pragma unroll
        for (int ks = 0; ks < 4; ++ks)
#pragma unroll
            for (int ct = 0; ct < 4; ++ct) {
                const int off = ((((ks * 4 + l4h) << 6) + (ct << 4) + l15) << 3);
                ch[ct][ks] = *reinterpret_cast<const s16x8*>(gp + off);
                cl[ct][ks] = *reinterpret_cast<const s16x8*>(gp + 8192 + off);
            }
    }
    float ekv[16];
#pragma unroll
    for (int ct = 0; ct < 4; ++ct)
#pragma unroll
        for (int e = 0; e < 4; ++e)
            ekv[ct * 4 + e] = esq[kbase + ct * 16 + l4h * 4 + e];

    const int rbase = chunk * 1024;
    float4* pq = pquad + (size_t)sub * BN;

#pragma unroll 1
    for (int t = 0; t < 64; ++t) {
        const int r0 = rbase + t * 16;
        s16x8 zh[4], zl[4];
#pragma unroll
        for (int ks = 0; ks < 4; ++ks) {
            const float* src = z + (size_t)(r0 + l15) * DN + ks * 32 + l4h * 8;
            const float4 v0 = *reinterpret_cast<const float4*>(src);
            const float4 v1 = *reinterpret_cast<const float4*>(src + 4);
            cvt8(v0, v1, zh[ks], zl[ks]);
        }
        tile_compute(ch, cl, zh, zl, ekv, kbase, r0, pq, l15, l4h);
    }
}

// ===========================================================================
// PHASE 2a (merge, R12-validated): 512 blocks x 256 threads, one row per
// thread, NO LDS, NO barriers. 16-way TOP-3 merge; tier-2 inline 2-chain
// exact rescore; tier-3 -> global rescue list; sampled canary -> flag.
// ===========================================================================
template <bool HZ>
__global__ __launch_bounds__(256, 2) void vq_merge3(const float* __restrict__ z,
                                                    const float* __restrict__ cb,
                                                    const float* __restrict__ esq,
                                                    const float* __restrict__ zsqArr,
                                                    const float4* __restrict__ pquad,
                                                    int* __restrict__ rmeta,
                                                    int* __restrict__ rlist,
                                                    float* __restrict__ out) {
    const int tid = threadIdx.x;
    const int r   = blockIdx.x * 256 + tid;

    float zsq;
    if constexpr (HZ) {
        zsq = zsqArr[r];
    } else {
        const float* zr = z + (size_t)r * DN;
        float a8[8];
#pragma unroll
        for (int c = 0; c < 32; ++c) {
            const float4 v = *reinterpret_cast<const float4*>(zr + c * 4);
            const int t0 = 4 * (c & 1);
            if (c < 2) {
                a8[t0 + 0] = __fmul_rn(v.x, v.x);
                a8[t0 + 1] = __fmul_rn(v.y, v.y);
                a8[t0 + 2] = __fmul_rn(v.z, v.z);
                a8[t0 + 3] = __fmul_rn(v.w, v.w);
            } else {
                a8[t0 + 0] = __fadd_rn(a8[t0 + 0], __fmul_rn(v.x, v.x));
                a8[t0 + 1] = __fadd_rn(a8[t0 + 1], __fmul_rn(v.y, v.y));
                a8[t0 + 2] = __fadd_rn(a8[t0 + 2], __fmul_rn(v.z, v.z));
                a8[t0 + 3] = __fadd_rn(a8[t0 + 3], __fmul_rn(v.w, v.w));
            }
        }
        zsq = __fadd_rn(
            __fadd_rn(__fadd_rn(a8[0], a8[1]), __fadd_rn(a8[2], a8[3])),
            __fadd_rn(__fadd_rn(a8[4], a8[5]), __fadd_rn(a8[6], a8[7])));
    }

    // ---- 16-way top-3 merge (validated insert; s ascending = code order) ---
    float B1 = INFINITY, B2 = INFINITY, B3 = INFINITY;
    int   I1 = 0, I2 = 0;
#pragma unroll
    for (int half = 0; half < 2; ++half) {
        float4 q[8];
#pragma unroll
        for (int s = 0; s < 8; ++s)
            q[s] = pquad[(size_t)(half * 8 + s) * BN + r];
#pragma unroll
        for (int s = 0; s < 8; ++s) {
            const int ii = __float_as_int(q[s].w);
            const int j1 = ii & 0xffff, j2 = ii >> 16;
            if (q[s].x < B1)      { B3 = B2; B2 = B1; I2 = I1; B1 = q[s].x; I1 = j1; }
            else if (q[s].x < B2) { B3 = B2; B2 = q[s].x; I2 = j1; }
            else if (q[s].x < B3) { B3 = q[s].x; }
            if (q[s].y < B2)      { B3 = B2; B2 = q[s].y; I2 = j2; }
            else if (q[s].y < B3) { B3 = q[s].y; }
            B3 = fminf(B3, q[s].z);
        }
    }

    int win = I1;
    if (B3 - B1 <= TAMB) {
        // tier 3 (rare): full exact rescan in the rescue kernel
        const int p = atomicAdd(&rmeta[0], 1);
        rlist[p] = r;
    } else if (B2 - B1 <= TAMB) {
        // tier 2: exact rescore of {I1, I2} (validated chain + tie rule)
        const float da = exact_d2_g(z, cb, r, I1, zsq, esq[I1]);
        const float db = exact_d2_g(z, cb, r, I2, zsq, esq[I2]);
        if (da < db) win = I1;
        else if (db < da) win = I2;
        else win = (I1 < I2) ? I1 : I2;
    }
    out[(size_t)BN * DN + 1 + r] = (float)win;

    // sampled canary: one row per wave; gross failure is systematic
    if ((tid & 63) == 0) {
        const float d2x  = exact_d2_g(z, cb, r, I1, zsq, esq[I1]);
        const float pred = __fadd_rn(zsq, B1);
        if (fabsf(pred - d2x) > CANARY) atomicExch(&rmeta[1], 1);
    }
}

// ===========================================================================
// PHASE 2b (rescue v2, COALESCED): one WAVE per flagged row, codes mapped
// k = c*64 + lane so each per-dim read of the TRANSPOSED codebook cbT is a
// consecutive-lane consecutive-float access (256B coalesced transactions;
// fixes R11's 64-line-per-load pattern). Per-code dot is the exact
// sequential reference fma chain over ascending d (identical rounding to
// exact_d2_g); d2 = fl(fl(zsq - fl(2*dot)) + esq). In-lane codes ascend in
// c (strict < keeps lowest); cross-lane lexicographic reduce (validated).
// Canary flag set -> rescans ALL rows (catastrophic-correctness path).
// ===========================================================================
template <bool HZ>
__global__ __launch_bounds__(256, 2) void vq_rescue2(const float* __restrict__ z,
                                                     const float* __restrict__ cbT,
                                                     const float* __restrict__ esq,
                                                     const float* __restrict__ zsqArr,
                                                     const int* __restrict__ rmeta,
                                                     const int* __restrict__ rlist,
                                                     float* __restrict__ out) {
    const int lane = threadIdx.x & 63;
    const int wid  = blockIdx.x * 4 + (threadIdx.x >> 6);
    const int nw   = gridDim.x * 4;
    const int n    = rmeta[0];
    const int flag = rmeta[1];
    const int total = flag ? BN : n;

    for (int ii = wid; ii < total; ii += nw) {
        const int row = flag ? ii : rlist[ii];
        float zsq;
        if constexpr (HZ) {
            zsq = zsqArr[row];
        } else {
            const float* zr0 = z + (size_t)row * DN;
            float a8[8];
#pragma unroll
            for (int c = 0; c < 32; ++c) {
                const float4 v = *reinterpret_cast<const float4*>(zr0 + c * 4);
                const int t0 = 4 * (c & 1);
                if (c < 2) {
                    a8[t0 + 0] = __fmul_rn(v.x, v.x);
                    a8[t0 + 1] = __fmul_rn(v.y, v.y);
                    a8[t0 + 2] = __fmul_rn(v.z, v.z);
                    a8[t0 + 3] = __fmul_rn(v.w, v.w);
                } else {
                    a8[t0 + 0] = __fadd_rn(a8[t0 + 0], __fmul_rn(v.x, v.x));
                    a8[t0 + 1] = __fadd_rn(a8[t0 + 1], __fmul_rn(v.y, v.y));
                    a8[t0 + 2] = __fadd_rn(a8[t0 + 2], __fmul_rn(v.z, v.z));
                    a8[t0 + 3] = __fadd_rn(a8[t0 + 3], __fmul_rn(v.w, v.w));
                }
            }
            zsq = __fadd_rn(
                __fadd_rn(__fadd_rn(a8[0], a8[1]), __fadd_rn(a8[2], a8[3])),
                __fadd_rn(__fadd_rn(a8[4], a8[5]), __fadd_rn(a8[6], a8[7])));
        }

        const float* zr = z + (size_t)row * DN;
        float acc[16];
#pragma unroll
        for (int c = 0; c < 16; ++c) acc[c] = 0.0f;
#pragma unroll 1
        for (int d = 0; d < DN; ++d) {
            const float zd = zr[d];                       // wave-uniform
            const float* cd = cbT + (size_t)d * KN + lane;
#pragma unroll
            for (int c = 0; c < 16; ++c)
                acc[c] = __fmaf_rn(zd, cd[c * 64], acc[c]);
        }
        // in-lane best: codes k = c*64+lane ascend in c; strict < keeps lowest
        float best = INFINITY; int bi = 0;
#pragma unroll
        for (int c = 0; c < 16; ++c) {
            const int k = c * 64 + lane;
            const float d2 = __fadd_rn(__fsub_rn(zsq, __fmul_rn(2.0f, acc[c])),
                                       esq[k]);
            if (d2 < best) { best = d2; bi = k; }
        }
#pragma unroll
        for (int m = 1; m < 64; m <<= 1) {
            const float ob  = __shfl_xor(best, m);
            const int   obi = __shfl_xor(bi, m);
            if (ob < best || (ob == best && obi < bi)) { best = ob; bi = obi; }
        }
        if (lane == 0) out[(size_t)BN * DN + 1 + row] = (float)bi;
    }
}

// ===========================================================================
// PHASE 2c (epilogue): pure streaming (R9/R12-validated). 2048 x 256.
// ===========================================================================
__global__ __launch_bounds__(256, 4) void vq_epilogue(const float* __restrict__ z,
                                                      const float* __restrict__ cb,
                                                      float* __restrict__ out,
                                                      double* __restrict__ partials) {
    __shared__ int sidx[EROWS];
    __shared__ double sls[256];
    const int tid  = threadIdx.x;
    const int row0 = blockIdx.x * EROWS;

    if (tid < EROWS)
        sidx[tid] = (int)out[(size_t)BN * DN + 1 + row0 + tid];
    __syncthreads();

    double ls = 0.0;
    const int j = tid & 31;
#pragma unroll
    for (int half = 0; half < 2; ++half) {
        float4 zb[4], cv[4];
        int rr[4];
#pragma unroll
        for (int u = 0; u < 4; ++u) {
            const int it = half * 4 + u;
            rr[u] = it * 8 + (tid >> 5);
            zb[u] = *reinterpret_cast<const float4*>(
                z + (size_t)(row0 + rr[u]) * DN + j * 4);
            cv[u] = *reinterpret_cast<const float4*>(
                cb + (size_t)sidx[rr[u]] * DN + j * 4);
        }
#pragma unroll
        for (int u = 0; u < 4; ++u) {
            *reinterpret_cast<float4*>(out + (size_t)(row0 + rr[u]) * DN + j * 4) = cv[u];
            const float d0 = __fsub_rn(cv[u].x, zb[u].x);
            const float d1 = __fsub_rn(cv[u].y, zb[u].y);
            const float d2e = __fsub_rn(cv[u].z, zb[u].z);
            const float d3 = __fsub_rn(cv[u].w, zb[u].w);
            ls += (double)__fmul_rn(d0, d0);
            ls += (double)__fmul_rn(d1, d1);
            ls += (double)__fmul_rn(d2e, d2e);
            ls += (double)__fmul_rn(d3, d3);
        }
    }
    sls[tid] = ls;
    __syncthreads();
    for (int s = 128; s > 0; s >>= 1) {
        if (tid < s) sls[tid] += sls[tid + s];
        __syncthreads();
    }
    if (tid == 0) partials[blockIdx.x] = sls[0];
}

#define UPD(s, sc, kk) { \
    const bool lt1 = (sc) < b1v[s]; \
    const bool lt2 = (sc) < b2v[s]; \
    const bool lt3 = (sc) < b3v[s]; \
    b3v[s] = lt2 ? b2v[s] : (lt3 ? (sc) : b3v[s]); \
    b2v[s] = lt1 ? b1v[s] : (lt2 ? (sc) : b2v[s]); \
    i2v[s] = lt1 ? i1v[s] : (lt2 ? (kk) : i2v[s]); \
    b1v[s] = lt1 ? (sc) : b1v[s]; \
    i1v[s] = lt1 ? (kk) : i1v[s]; }

// ---------------------------------------------------------------------------
// Fallback (small workspace): validated R2-structure LDS kernel, in-kernel cvt.
// ---------------------------------------------------------------------------
__global__ __launch_bounds__(256, 2) void vq_lds(const float* __restrict__ z,
                                                 const float* __restrict__ cb,
                                                 const float* __restrict__ esq,
                                                 float* __restrict__ out,
                                                 double* __restrict__ partials) {
    __shared__ __align__(16) short cbS[2][16384];
    __shared__ __align__(16) float sEsq[KN];
    __shared__ float  szsq[ROWS];
    __shared__ float  sB1[2][ROWS], sB2[2][ROWS], sB3[2][ROWS];
    __shared__ int    sI1[2][ROWS], sI2[2][ROWS];
    __shared__ int    sbidx[ROWS];
    __shared__ int    t2list[ROWS], t3list[ROWS];
    __shared__ int    t2n, t3n;
    __shared__ double sls[256];

    const int tid  = threadIdx.x;
    const int lane = tid & 63;
    const int w    = tid >> 6;
    const int l15  = lane & 15;
    const int l4h  = lane >> 4;
    const int wr   = w >> 1;
    const int wc   = w & 1;
    const int row0 = blockIdx.x * ROWS;

    if (tid == 0) { t2n = 0; t3n = 0; }
#pragma unroll
    for (int i = 0; i < 4; ++i) sEsq[i * 256 + tid] = esq[i * 256 + tid];

    float4 stg[8];
#pragma unroll
    for (int i = 0; i < 4; ++i) {
        const int mc = i * 256 + tid, m = mc >> 6, c = mc & 63;
        const float* src = cb + ((size_t)c) * DN + m * 8;
        stg[2 * i]     = *reinterpret_cast<const float4*>(src);
        stg[2 * i + 1] = *reinterpret_cast<const float4*>(src + 4);
    }

    if (tid < ROWS) {
        const float* zr = z + (size_t)(row0 + tid) * DN;
        float rr[8];
#pragma unroll
        for (int c = 0; c < 32; ++c) {
            const float4 v = *reinterpret_cast<const float4*>(zr + c * 4);
            const int t0 = 4 * (c & 1);
            if (c < 2) {
                rr[t0 + 0] = __fmul_rn(v.x, v.x);
                rr[t0 + 1] = __fmul_rn(v.y, v.y);
                rr[t0 + 2] = __fmul_rn(v.z, v.z);
                rr[t0 + 3] = __fmul_rn(v.w, v.w);
            } else {
                rr[t0 + 0] = __fadd_rn(rr[t0 + 0], __fmul_rn(v.x, v.x));
                rr[t0 + 1] = __fadd_rn(rr[t0 + 1], __fmul_rn(v.y, v.y));
                rr[t0 + 2] = __fadd_rn(rr[t0 + 2], __fmul_rn(v.z, v.z));
                rr[t0 + 3] = __fadd_rn(rr[t0 + 3], __fmul_rn(v.w, v.w));
            }
        }
        szsq[tid] = __fadd_rn(
            __fadd_rn(__fadd_rn(rr[0], rr[1]), __fadd_rn(rr[2], rr[3])),
            __fadd_rn(__fadd_rn(rr[4], rr[5]), __fadd_rn(rr[6], rr[7])));
    }

    {
        short* dst = &cbS[0][0];
#pragma unroll
        for (int i = 0; i < 4; ++i) {
            const int mc = i * 256 + tid, m = mc >> 6, c = mc & 63;
            s16x4 h0, l0, h1, l1;
            cvt4(stg[2 * i], h0, l0); cvt4(stg[2 * i + 1], h1, l1);
            short* hb = dst + (m * 64 + c) * 8;
            *reinterpret_cast<s16x4*>(hb)     = h0;
            *reinterpret_cast<s16x4*>(hb + 4) = h1;
            short* lb = hb + 8192;
            *reinterpret_cast<s16x4*>(lb)     = l0;
            *reinterpret_cast<s16x4*>(lb + 4) = l1;
        }
    }

    s16x8 zha[2][4], zla[2][4];
#pragma unroll
    for (int rt = 0; rt < 2; ++rt) {
#pragma unroll
        for (int ks = 0; ks < 4; ++ks) {
            const int rl = row0 + wr * 32 + rt * 16 + l15;
            const float* src = z + (size_t)rl * DN + ks * 32 + l4h * 8;
            const float4 v0 = *reinterpret_cast<const float4*>(src);
            const float4 v1 = *reinterpret_cast<const float4*>(src + 4);
            cvt8(v0, v1, zha[rt][ks], zla[rt][ks]);
        }
    }
    __syncthreads();

    float b1v[8], b2v[8], b3v[8]; int i1v[8], i2v[8];
#pragma unroll
    for (int s = 0; s < 8; ++s) {
        b1v[s] = INFINITY; b2v[s] = INFINITY; b3v[s] = INFINITY;
        i1v[s] = 0; i2v[s] = 0;
    }

    for (int g = 0; g < NGRP; ++g) {
        const int buf = g & 1;
        if (g < NGRP - 1) {
            const int gb = (g + 1) * GCODES;
#pragma unroll
            for (int i = 0; i < 4; ++i) {
                const int mc = i * 256 + tid, m = mc >> 6, c = mc & 63;
                const float* src = cb + ((size_t)(gb + c)) * DN + m * 8;
                stg[2 * i]     = *reinterpret_cast<const float4*>(src);
                stg[2 * i + 1] = *reinterpret_cast<const float4*>(src + 4);
            }
        }

        f32x4 acc[2][2];
#pragma unroll
        for (int rt = 0; rt < 2; ++rt)
#pragma unroll
            for (int ct = 0; ct < 2; ++ct)
                acc[rt][ct] = (f32x4){0.0f, 0.0f, 0.0f, 0.0f};

#pragma unroll
        for (int ks = 0; ks < 4; ++ks) {
            const int b0 = (((ks * 4 + l4h) << 6) + (wc << 5) + l15) << 3;
            const s16x8 bh0 = *reinterpret_cast<const s16x8*>(&cbS[buf][b0]);
            const s16x8 bl0 = *reinterpret_cast<const s16x8*>(&cbS[buf][8192 + b0]);
            const s16x8 bh1 = *reinterpret_cast<const s16x8*>(&cbS[buf][b0 + 128]);
            const s16x8 bl1 = *reinterpret_cast<const s16x8*>(&cbS[buf][8192 + b0 + 128]);
            acc[0][0] = __builtin_amdgcn_mfma_f32_16x16x32_bf16(zha[0][ks], bh0, acc[0][0], 0, 0, 0);
            acc[0][0] = __builtin_amdgcn_mfma_f32_16x16x32_bf16(zla[0][ks], bh0, acc[0][0], 0, 0, 0);
            acc[0][0] = __builtin_amdgcn_mfma_f32_16x16x32_bf16(zha[0][ks], bl0, acc[0][0], 0, 0, 0);
            acc[1][0] = __builtin_amdgcn_mfma_f32_16x16x32_bf16(zha[1][ks], bh0, acc[1][0], 0, 0, 0);
            acc[1][0] = __builtin_amdgcn_mfma_f32_16x16x32_bf16(zla[1][ks], bh0, acc[1][0], 0, 0, 0);
            acc[1][0] = __builtin_amdgcn_mfma_f32_16x16x32_bf16(zha[1][ks], bl0, acc[1][0], 0, 0, 0);
            acc[0][1] = __builtin_amdgcn_mfma_f32_16x16x32_bf16(zha[0][ks], bh1, acc[0][1], 0, 0, 0);
            acc[0][1] = __builtin_amdgcn_mfma_f32_16x16x32_bf16(zla[0][ks], bh1, acc[0][1], 0, 0, 0);
            acc[0][1] = __builtin_amdgcn_mfma_f32_16x16x32_bf16(zha[0][ks], bl1, acc[0][1], 0, 0, 0);
            acc[1][1] = __builtin_amdgcn_mfma_f32_16x16x32_bf16(zha[1][ks], bh1, acc[1][1], 0, 0, 0);
            acc[1][1] = __builtin_amdgcn_mfma_f32_16x16x32_bf16(zla[1][ks], bh1, acc[1][1], 0, 0, 0);
            acc[1][1] = __builtin_amdgcn_mfma_f32_16x16x32_bf16(zha[1][ks], bl1, acc[1][1], 0, 0, 0);
        }

#pragma unroll
        for (int ct = 0; ct < 2; ++ct) {
            const int k = g * GCODES + wc * 32 + ct * 16 + l15;
            const float ek = sEsq[k];
#pragma unroll
            for (int rt = 0; rt < 2; ++rt) {
#pragma unroll
                for (int e = 0; e < 4; ++e) {
                    const float sc = __fmaf_rn(-2.0f, acc[rt][ct][e], ek);
                    UPD(rt * 4 + e, sc, k)
                }
            }
        }

        if (g < NGRP - 1) {
            short* dst = &cbS[buf ^ 1][0];
#pragma unroll
            for (int i = 0; i < 4; ++i) {
                const int mc = i * 256 + tid, m = mc >> 6, c = mc & 63;
                s16x4 h0, l0, h1, l1;
                cvt4(stg[2 * i], h0, l0); cvt4(stg[2 * i + 1], h1, l1);
                short* hb = dst + (m * 64 + c) * 8;
                *reinterpret_cast<s16x4*>(hb)     = h0;
                *reinterpret_cast<s16x4*>(hb + 4) = h1;
                short* lb = hb + 8192;
                *reinterpret_cast<s16x4*>(lb)     = l0;
                *reinterpret_cast<s16x4*>(lb + 4) = l1;
            }
        }
        __syncthreads();
    }

#pragma unroll
    for (int st = 1; st < 16; st <<= 1) {
#pragma unroll
        for (int s = 0; s < 8; ++s) {
            const float ob1 = __shfl_xor(b1v[s], st);
            const int   oi1 = __shfl_xor(i1v[s], st);
            const float ob2 = __shfl_xor(b2v[s], st);
            const int   oi2 = __shfl_xor(i2v[s], st);
            const float ob3 = __shfl_xor(b3v[s], st);
            float v1, v2, v3; int j1, j2;
            if (ob1 < b1v[s]) {
                v1 = ob1; j1 = oi1;
                if (b1v[s] < ob2) { v2 = b1v[s]; j2 = i1v[s]; v3 = fminf(b2v[s], ob2); }
                else              { v2 = ob2;    j2 = oi2;    v3 = fminf(b1v[s], ob3); }
            } else {
                v1 = b1v[s]; j1 = i1v[s];
                if (ob1 < b2v[s]) { v2 = ob1;    j2 = oi1;    v3 = fminf(ob2, b2v[s]); }
                else              { v2 = b2v[s]; j2 = i2v[s]; v3 = fminf(ob1, b3v[s]); }
            }
            b1v[s] = v1; i1v[s] = j1; b2v[s] = v2; i2v[s] = j2; b3v[s] = v3;
        }
    }
    if (l15 == 0) {
#pragma unroll
        for (int s = 0; s < 8; ++s) {
            const int r = wr * 32 + (s >> 2) * 16 + l4h * 4 + (s & 3);
            sB1[wc][r] = b1v[s]; sI1[wc][r] = i1v[s];
            sB2[wc][r] = b2v[s]; sI2[wc][r] = i2v[s];
            sB3[wc][r] = b3v[s];
        }
    }
    __syncthreads();

    if (tid < ROWS) {
        const float a1 = sB1[0][tid]; const int aj1 = sI1[0][tid];
        const float a2 = sB2[0][tid]; const int aj2 = sI2[0][tid];
        const float a3 = sB3[0][tid];
        const float c1 = sB1[1][tid]; const int cj1 = sI1[1][tid];
        const float c2 = sB2[1][tid]; const int cj2 = sI2[1][tid];
        const float c3 = sB3[1][tid];
        float b1, b2, b3; int i1, i2;
        if (a1 <= c1) {
            b1 = a1; i1 = aj1;
            if (a2 <= c1) { b2 = a2; i2 = aj2; b3 = fminf(a3, c1); }
            else          { b2 = c1; i2 = cj1; b3 = fminf(a2, c2); }
        } else {
            b1 = c1; i1 = cj1;
            if (c2 <= a1) { b2 = c2; i2 = cj2; b3 = fminf(c3, a1); }
            else          { b2 = a1; i2 = aj1; b3 = fminf(c2, a2); }
        }
        sbidx[tid] = i1;
        sI1[0][tid] = i1; sI2[0][tid] = i2;
        const float d2x  = exact_d2_g(z, cb, row0 + tid, i1, szsq[tid], sEsq[i1]);
        const float pred = __fadd_rn(szsq[tid], b1);
        const bool bad   = fabsf(pred - d2x) > CANARY;
        if (bad || (b3 - b1 <= TAMB)) {
            const int p = atomicAdd(&t3n, 1); t3list[p] = tid;
        } else if (b2 - b1 <= TAMB) {
            const int p = atomicAdd(&t2n, 1); t2list[p] = tid;
        }
    }
    __syncthreads();

    if (tid < t2n) {
        const int r  = t2list[tid];
        const int ka = sI1[0][r], kb = sI2[0][r];
        const float zsq = szsq[r];
        const float da = exact_d2_g(z, cb, row0 + r, ka, zsq, sEsq[ka]);
        const float db = exact_d2_g(z, cb, row0 + r, kb, zsq, sEsq[kb]);
        int win;
        if (da < db) win = ka;
        else if (db < da) win = kb;
        else win = (ka < kb) ? ka : kb;
        sbidx[r] = win;
    }
    for (int ii = w; ii < t3n; ii += 4) {
        const int r = t3list[ii];
        const float zsq = szsq[r];
        float best = INFINITY; int bi = 0;
#pragma unroll 1
        for (int kk = 0; kk < 16; ++kk) {
            const int k = lane * 16 + kk;
            const float d2v = exact_d2_g(z, cb, row0 + r, k, zsq, sEsq[k]);
            if (d2v < best) { best = d2v; bi = k; }
        }
#pragma unroll
        for (int m = 1; m < 64; m <<= 1) {
            const float ob  = __shfl_xor(best, m);
            const int   obi = __shfl_xor(bi, m);
            if (ob < best || (ob == best && obi < bi)) { best = ob; bi = obi; }
        }
        if (lane == 0) sbidx[r] = bi;
    }
    __syncthreads();

    if (tid < ROWS)
        out[(size_t)BN * DN + 1 + row0 + tid] = (float)sbidx[tid];

    double ls = 0.0;
#pragma unroll
    for (int it = 0; it < 8; ++it) {
        const int r = it * 8 + (tid >> 5);
        const int j = tid & 31;
        const float4 zv = *reinterpret_cast<const float4*>(
            z + ((size_t)(row0 + r)) * DN + j * 4);
        const int bfin = sbidx[r];
        const float4 cv = *reinterpret_cast<const float4*>(
            cb + ((size_t)bfin) * DN + j * 4);
        *reinterpret_cast<float4*>(out + ((size_t)(row0 + r)) * DN + j * 4) = cv;
        const float d0 = __fsub_rn(cv.x, zv.x);
        const float d1 = __fsub_rn(cv.y, zv.y);
        const float d2e = __fsub_rn(cv.z, zv.z);
        const float d3 = __fsub_rn(cv.w, zv.w);
        ls += (double)__fmul_rn(d0, d0);
        ls += (double)__fmul_rn(d1, d1);
        ls += (double)__fmul_rn(d2e, d2e);
        ls += (double)__fmul_rn(d3, d3);
    }
    sls[tid] = ls;
    __syncthreads();
    for (int s = 128; s > 0; s >>= 1) {
        if (tid < s) sls[tid] += sls[tid + s];
        __syncthreads();
    }
    if (tid == 0) partials[blockIdx.x] = sls[0];
}

// ---------------------------------------------------------------------------
// Final loss reduction over n block partials (deterministic)
// ---------------------------------------------------------------------------
__global__ __launch_bounds__(256) void loss_kernel(const double* __restrict__ partials,
                                                   float* __restrict__ out, int n) {
    __shared__ double s[256];
    double acc = 0.0;
    for (int i = threadIdx.x; i < n; i += 256) acc += partials[i];
    s[threadIdx.x] = acc;
    __syncthreads();
    for (int t = 128; t > 0; t >>= 1) {
        if (threadIdx.x < t) s[threadIdx.x] += s[threadIdx.x + t];
        __syncthreads();
    }
    if (threadIdx.x == 0)
        out[(size_t)BN * DN] = (float)(s[0] / ((double)BN * (double)DN));
}

extern "C" void kernel_launch(void* const* d_in, const int* in_sizes, int n_in,
                              void* d_out, int out_size, void* d_ws, size_t ws_size,
                              hipStream_t stream) {
    const float* z  = (const float*)d_in[0];
    const float* cb = (const float*)d_in[1];
    float* out = (float*)d_out;

    // Workspace layout:
    //   [0, 4096)                esq
    //   [4096, 20480)            2048 double partials
    //   [20480, 544768)          cb planes (512KB)
    //   [544768, 34099200)       pquad: 16 x BN x float4 (32MB)
    //   [34099200, 34099328)     rmeta: rcount, gflag
    //   [34099328, 34623616)     rlist (512KB)
    //   [34623616, 35147904)     cbT fp32 transposed (512KB) == need_mid
    //   [35147904, 35672192)     zsq (512KB)
    //   [35672192, 102781056)    z planes (64MB)             == need_full
    float*          esq      = (float*)d_ws;
    double*         partials = (double*)((char*)d_ws + 4096);
    unsigned short* cbpl     = (unsigned short*)((char*)d_ws + 20480);
    float4*         pquad    = (float4*)((char*)d_ws + 544768);
    int*            rmeta    = (int*)((char*)d_ws + 34099200ull);
    int*            rlist    = (int*)((char*)d_ws + 34099328ull);
    float*          cbT      = (float*)((char*)d_ws + 34623616ull);
    float*          zsqArr   = (float*)((char*)d_ws + 35147904ull);
    unsigned short* zpl      = (unsigned short*)((char*)d_ws + 35672192ull);
    const size_t need_mid  = 35147904ull;
    const size_t need_full = 102781056ull;

    esq_kernel<<<KN / 256, 256, 0, stream>>>(cb, esq);
    if (ws_size >= need_full) {
        cvt_kernel  <<<64, 256, 0, stream>>>(cb, cbpl);
        cvtT_kernel <<<512, 256, 0, stream>>>(cb, cbT);
        zprep_kernel<<<BN / 256, 256, 0, stream>>>(z, zpl, zsqArr);
        vq_score_pre<<<1024, 256, 0, stream>>>(zpl, cbpl, esq, pquad);
        hipMemsetAsync(rmeta, 0, 8, stream);
        vq_merge3<true>  <<<512, 256, 0, stream>>>(z, cb, esq, zsqArr, pquad, rmeta, rlist, out);
        vq_rescue2<true> <<<512, 256, 0, stream>>>(z, cbT, esq, zsqArr, rmeta, rlist, out);
        vq_epilogue <<<EBLK, 256, 0, stream>>>(z, cb, out, partials);
        loss_kernel <<<1, 256, 0, stream>>>(partials, out, EBLK);
    } else if (ws_size >= need_mid) {
        cvt_kernel <<<64, 256, 0, stream>>>(cb, cbpl);
        cvtT_kernel<<<512, 256, 0, stream>>>(cb, cbT);
        vq_score   <<<512, 256, 0, stream>>>(z, cbpl, esq, pquad);
        hipMemsetAsync(rmeta, 0, 8, stream);
        vq_merge3<false>  <<<512, 256, 0, stream>>>(z, cb, esq, nullptr, pquad, rmeta, rlist, out);
        vq_rescue2<false> <<<512, 256, 0, stream>>>(z, cbT, esq, nullptr, rmeta, rlist, out);
        vq_epilogue<<<EBLK, 256, 0, stream>>>(z, cb, out, partials);
        loss_kernel<<<1, 256, 0, stream>>>(partials, out, EBLK);
    } else {
        vq_lds<<<NBLK, 256, 0, stream>>>(z, cb, esq, out, partials);
        loss_kernel<<<1, 256, 0, stream>>>(partials, out, NBLK);
    }
}

// Round 14
// 220.297 us; speedup vs baseline: 3.2980x; 1.0501x over previous
//
#include <hip/hip_runtime.h>
#include <math.h>

// Problem constants
#define BN 131072
#define KN 1024
#define DN 128
#define GCODES 64
#define NGRP (KN / GCODES)

// epilogue geometry
#define EROWS 64
#define EBLK (BN / EROWS)     // 2048

// fallback geometry
#define ROWS 64
#define NBLK (BN / ROWS)      // 2048

// Ambiguity threshold on approx scores (esq - 2*dot).
#define TAMB 2.5e-4f
// Canary: gross mismatch (e.g. wrong MFMA layout) -> full exact rescan.
#define CANARY 0.01f

typedef __attribute__((ext_vector_type(8))) short s16x8;   // 8 bf16 (4 VGPR)
typedef __attribute__((ext_vector_type(4))) short s16x4;   // 4 bf16 (8B)
typedef __attribute__((ext_vector_type(4))) float f32x4;   // MFMA C/D

__device__ __forceinline__ unsigned short f2bf(float f) {
    const unsigned int u = __float_as_uint(f);
    return (unsigned short)((u + 0x7fffu + ((u >> 16) & 1u)) >> 16);
}
__device__ __forceinline__ float bf2f(unsigned short s) {
    return __uint_as_float(((unsigned int)s) << 16);
}
__device__ __forceinline__ void cvt4(const float4 v, s16x4& h4, s16x4& l4) {
    const unsigned short h0 = f2bf(v.x), h1 = f2bf(v.y), h2 = f2bf(v.z), h3 = f2bf(v.w);
    h4[0] = (short)h0; h4[1] = (short)h1; h4[2] = (short)h2; h4[3] = (short)h3;
    l4[0] = (short)f2bf(v.x - bf2f(h0));
    l4[1] = (short)f2bf(v.y - bf2f(h1));
    l4[2] = (short)f2bf(v.z - bf2f(h2));
    l4[3] = (short)f2bf(v.w - bf2f(h3));
}
__device__ __forceinline__ void cvt8(const float4 v0, const float4 v1,
                                     s16x8& h, s16x8& l) {
    s16x4 h0, l0, h1, l1;
    cvt4(v0, h0, l0); cvt4(v1, h1, l1);
    h[0]=h0[0]; h[1]=h0[1]; h[2]=h0[2]; h[3]=h0[3];
    h[4]=h1[0]; h[5]=h1[1]; h[6]=h1[2]; h[7]=h1[3];
    l[0]=l0[0]; l[1]=l0[1]; l[2]=l0[2]; l[3]=l0[3];
    l[4]=l1[0]; l[5]=l1[1]; l[6]=l1[2]; l[7]=l1[3];
}

// ---------------------------------------------------------------------------
// e_sq[k] = np.sum(codebook[k]^2), numpy pairwise_sum semantics (verified)
// ---------------------------------------------------------------------------
__global__ __launch_bounds__(256) void esq_kernel(const float* __restrict__ cb,
                                                  float* __restrict__ esq) {
    int k = blockIdx.x * 256 + threadIdx.x;
    if (k >= KN) return;
    const float* row = cb + (size_t)k * DN;
    float r[8];
#pragma unroll
    for (int j = 0; j < 8; ++j) r[j] = __fmul_rn(row[j], row[j]);
#pragma unroll
    for (int i = 8; i < DN; i += 8) {
#pragma unroll
        for (int j = 0; j < 8; ++j)
            r[j] = __fadd_rn(r[j], __fmul_rn(row[i + j], row[i + j]));
    }
    esq[k] = __fadd_rn(
        __fadd_rn(__fadd_rn(r[0], r[1]), __fadd_rn(r[2], r[3])),
        __fadd_rn(__fadd_rn(r[4], r[5]), __fadd_rn(r[6], r[7])));
}

// ---------------------------------------------------------------------------
// One-shot codebook conversion -> bf16 hi/lo planes, fragment-linear
// chunk-major per 64-code group.
// ---------------------------------------------------------------------------
__global__ __launch_bounds__(256) void cvt_kernel(const float* __restrict__ cb,
                                                  unsigned short* __restrict__ pl) {
    const int t = blockIdx.x * 256 + threadIdx.x;     // 16384 threads
    const int g = t >> 10, rem = t & 1023;
    const int m = rem >> 6, c = rem & 63;
    const float* src = cb + ((size_t)(g * 64 + c)) * DN + m * 8;
    const float4 v0 = *reinterpret_cast<const float4*>(src);
    const float4 v1 = *reinterpret_cast<const float4*>(src + 4);
    s16x8 h, l;
    cvt8(v0, v1, h, l);
    unsigned short* hb = pl + (size_t)g * 16384 + (m * 64 + c) * 8;
    *reinterpret_cast<s16x8*>(hb)        = h;
    *reinterpret_cast<s16x8*>(hb + 8192) = l;
}

// ---------------------------------------------------------------------------
// One-shot fp32 codebook transpose: cbT[d*KN + k] = cb[k*DN + d].
// ---------------------------------------------------------------------------
__global__ __launch_bounds__(256) void cvtT_kernel(const float* __restrict__ cb,
                                                   float* __restrict__ cbT) {
    const int idx = blockIdx.x * 256 + threadIdx.x;   // 131072 threads
    const int d = idx >> 10, k = idx & 1023;
    cbT[idx] = cb[(size_t)k * DN + d];
}

// ---------------------------------------------------------------------------
// z prep: zsq (exact numpy pairwise) + z hi/lo bf16 planes per-16-row tile.
// ---------------------------------------------------------------------------
__global__ __launch_bounds__(256) void zprep_kernel(const float* __restrict__ z,
                                                    unsigned short* __restrict__ zp,
                                                    float* __restrict__ zsq) {
    const int row = blockIdx.x * 256 + threadIdx.x;       // 512 blocks
    const float* zr = z + (size_t)row * DN;
    const int gt = row >> 4, rr = row & 15;
    unsigned short* hb = zp + (size_t)gt * 4096 + rr * 8;
    float a8[8];
#pragma unroll
    for (int m = 0; m < 16; ++m) {
        const float4 v0 = *reinterpret_cast<const float4*>(zr + m * 8);
        const float4 v1 = *reinterpret_cast<const float4*>(zr + m * 8 + 4);
        s16x8 h, l;
        cvt8(v0, v1, h, l);
        *reinterpret_cast<s16x8*>(hb + m * 128)        = h;
        *reinterpret_cast<s16x8*>(hb + 2048 + m * 128) = l;
        if (m == 0) {
            a8[0] = __fmul_rn(v0.x, v0.x); a8[1] = __fmul_rn(v0.y, v0.y);
            a8[2] = __fmul_rn(v0.z, v0.z); a8[3] = __fmul_rn(v0.w, v0.w);
            a8[4] = __fmul_rn(v1.x, v1.x); a8[5] = __fmul_rn(v1.y, v1.y);
            a8[6] = __fmul_rn(v1.z, v1.z); a8[7] = __fmul_rn(v1.w, v1.w);
        } else {
            a8[0] = __fadd_rn(a8[0], __fmul_rn(v0.x, v0.x));
            a8[1] = __fadd_rn(a8[1], __fmul_rn(v0.y, v0.y));
            a8[2] = __fadd_rn(a8[2], __fmul_rn(v0.z, v0.z));
            a8[3] = __fadd_rn(a8[3], __fmul_rn(v0.w, v0.w));
            a8[4] = __fadd_rn(a8[4], __fmul_rn(v1.x, v1.x));
            a8[5] = __fadd_rn(a8[5], __fmul_rn(v1.y, v1.y));
            a8[6] = __fadd_rn(a8[6], __fmul_rn(v1.z, v1.z));
            a8[7] = __fadd_rn(a8[7], __fmul_rn(v1.w, v1.w));
        }
    }
    zsq[row] = __fadd_rn(
        __fadd_rn(__fadd_rn(a8[0], a8[1]), __fadd_rn(a8[2], a8[3])),
        __fadd_rn(__fadd_rn(a8[4], a8[5]), __fadd_rn(a8[6], a8[7])));
}

// ---------------------------------------------------------------------------
// Bit-exact d2 (reference semantics): sequential fma chain d=0..127 ascending;
// d2 = fl(fl(zsq - fl(2*dot)) + esq). unroll 4 bounds register pressure.
// ---------------------------------------------------------------------------
__device__ __forceinline__ float exact_d2_g(const float* __restrict__ z,
                                            const float* __restrict__ cb,
                                            const int grow, const int k,
                                            const float zsq, const float ek) {
    const float* zr = z + (size_t)grow * DN;
    const float* cr = cb + (size_t)k * DN;
    float dot = 0.0f;
#pragma unroll 4
    for (int j = 0; j < 32; ++j) {
        const float4 zv = *reinterpret_cast<const float4*>(zr + j * 4);
        const float4 cv = *reinterpret_cast<const float4*>(cr + j * 4);
        dot = __fmaf_rn(zv.x, cv.x, dot);
        dot = __fmaf_rn(zv.y, cv.y, dot);
        dot = __fmaf_rn(zv.z, cv.z, dot);
        dot = __fmaf_rn(zv.w, cv.w, dot);
    }
    return __fadd_rn(__fsub_rn(zsq, __fmul_rn(2.0f, dot)), ek);
}

// ---------------------------------------------------------------------------
// Per-tile MFMA + TOP-3 FIN + partial store. med3-based insert: for sorted
// b1<=b2<=b3 and candidate sc,
//   b3' = med3(sc,b2,b3), b2' = med3(sc,b1,b2), b1' = min(sc,b1)
// -- case-by-case identical values to the validated select-chain insert
// (med3/min are exact); index updates use the same lt1/lt2 conditions ->
// I1/I2 bit-identical. 8 VALU/candidate vs 11.
// pquad format: (b1, b2, b3, bits(i2<<16|i1)).
// ---------------------------------------------------------------------------
__device__ __forceinline__ void tile_compute(const s16x8 (&ch)[4][4],
                                             const s16x8 (&cl)[4][4],
                                             const s16x8 (&zh)[4],
                                             const s16x8 (&zl)[4],
                                             const float (&ekv)[16],
                                             const int kbase, const int r0,
                                             float4* __restrict__ pq,
                                             const int l15, const int l4h) {
    f32x4 acc[4];
#pragma unroll
    for (int ct = 0; ct < 4; ++ct) acc[ct] = (f32x4){0.0f, 0.0f, 0.0f, 0.0f};
    __builtin_amdgcn_s_setprio(1);
#pragma unroll
    for (int ks = 0; ks < 4; ++ks) {
#pragma unroll
        for (int ct = 0; ct < 4; ++ct) {
            acc[ct] = __builtin_amdgcn_mfma_f32_16x16x32_bf16(ch[ct][ks], zh[ks], acc[ct], 0, 0, 0);
            acc[ct] = __builtin_amdgcn_mfma_f32_16x16x32_bf16(cl[ct][ks], zh[ks], acc[ct], 0, 0, 0);
            acc[ct] = __builtin_amdgcn_mfma_f32_16x16x32_bf16(ch[ct][ks], zl[ks], acc[ct], 0, 0, 0);
        }
    }
    __builtin_amdgcn_s_setprio(0);
    float b1 = INFINITY, b2 = INFINITY, b3 = INFINITY;
    int   i1 = 0, i2 = 0;
#pragma unroll
    for (int ct = 0; ct < 4; ++ct) {
#pragma unroll
        for (int e = 0; e < 4; ++e) {
            const float sc = __fmaf_rn(-2.0f, acc[ct][e], ekv[ct * 4 + e]);
            const int   kk = kbase + ct * 16 + l4h * 4 + e;
            const bool lt1 = sc < b1;
            const bool lt2 = sc < b2;
            const float nb3 = __builtin_amdgcn_fmed3f(sc, b2, b3);
            const float nb2 = __builtin_amdgcn_fmed3f(sc, b1, b2);
            i2 = lt1 ? i1 : (lt2 ? kk : i2);
            b3 = nb3;
            b2 = nb2;
            b1 = fminf(sc, b1);
            i1 = lt1 ? kk : i1;
        }
    }
#pragma unroll
    for (int st = 16; st < 64; st <<= 1) {
        const float ob1 = __shfl_xor(b1, st);
        const int   oi1 = __shfl_xor(i1, st);
        const float ob2 = __shfl_xor(b2, st);
        const int   oi2 = __shfl_xor(i2, st);
        const float ob3 = __shfl_xor(b3, st);
        float v1, v2, v3; int j1, j2;
        if (ob1 < b1) {
            v1 = ob1; j1 = oi1;
            if (b1 < ob2) { v2 = b1;  j2 = i1;  v3 = fminf(b2, ob2); }
            else          { v2 = ob2; j2 = oi2; v3 = fminf(b1, ob3); }
        } else {
            v1 = b1; j1 = i1;
            if (ob1 < b2) { v2 = ob1; j2 = oi1; v3 = fminf(ob2, b2); }
            else          { v2 = b2;  j2 = i2;  v3 = fminf(ob1, b3); }
        }
        b1 = v1; i1 = j1; b2 = v2; i2 = j2; b3 = v3;
    }
    if (l4h == 0) {
        float4 q;
        q.x = b1; q.y = b2; q.z = b3;
        q.w = __int_as_float((i2 << 16) | i1);
        pq[r0 + l15] = q;
    }
}

__device__ __forceinline__ void tile_load_zp(const unsigned short* __restrict__ zb,
                                             s16x8 (&zh)[4], s16x8 (&zl)[4]) {
#pragma unroll
    for (int ks = 0; ks < 4; ++ks) {
        zh[ks] = *reinterpret_cast<const s16x8*>(zb + ks * 512);
        zl[ks] = *reinterpret_cast<const s16x8*>(zb + 2048 + ks * 512);
    }
}

// ===========================================================================
// PHASE 1 (full path, R10-validated geometry): codes-in-registers scorer
// reading PRE-CONVERTED z. Grid 1024 = sliceW*256 + chunk2; 32 tiles/block.
// ===========================================================================
__global__ __launch_bounds__(256, 2) void vq_score_pre(const unsigned short* __restrict__ zp,
                                                       const unsigned short* __restrict__ planes,
                                                       const float* __restrict__ esq,
                                                       float4* __restrict__ pquad) {
    const int tid  = threadIdx.x;
    const int lane = tid & 63;
    const int w    = tid >> 6;
    const int l15  = lane & 15;
    const int l4h  = lane >> 4;
    const int sliceW = blockIdx.x >> 8;       // 0..3
    const int chunk2 = blockIdx.x & 255;      // 0..255 (32-tile chunk)
    const int sub    = sliceW * 4 + w;
    const int kbase  = sub * 64;

    s16x8 ch[4][4], cl[4][4];
    {
        const unsigned short* gp = planes + (size_t)sub * 16384;
#pragma unroll
        for (int ks = 0; ks < 4; ++ks)
#pragma unroll
            for (int ct = 0; ct < 4; ++ct) {
                const int off = ((((ks * 4 + l4h) << 6) + (ct << 4) + l15) << 3);
                ch[ct][ks] = *reinterpret_cast<const s16x8*>(gp + off);
                cl[ct][ks] = *reinterpret_cast<const s16x8*>(gp + 8192 + off);
            }
    }
    float ekv[16];
#pragma unroll
    for (int ct = 0; ct < 4; ++ct)
#pragma unroll
        for (int e = 0; e < 4; ++e)
            ekv[ct * 4 + e] = esq[kbase + ct * 16 + l4h * 4 + e];

    const int cbase = chunk2 * 32;
    const int rbase = chunk2 * 512;
    float4* pq = pquad + (size_t)sub * BN;
    const unsigned short* zpl = zp + l4h * 128 + l15 * 8;

    s16x8 hA[4], lA[4], hB[4], lB[4];
    tile_load_zp(zpl + (size_t)cbase * 4096, hA, lA);
#pragma unroll 1
    for (int t = 0; t < 32; t += 2) {
        tile_load_zp(zpl + (size_t)(cbase + t + 1) * 4096, hB, lB);
        tile_compute(ch, cl, hA, lA, ekv, kbase, rbase + t * 16, pq, l15, l4h);
        const int tn = (t + 2 < 32) ? t + 2 : 31;
        tile_load_zp(zpl + (size_t)(cbase + tn) * 4096, hA, lA);
        tile_compute(ch, cl, hB, lB, ekv, kbase, rbase + (t + 1) * 16, pq, l15, l4h);
    }
}

// ===========================================================================
// PHASE 1 (mid path): same scorer with in-kernel z cvt.
// ===========================================================================
__global__ __launch_bounds__(256, 2) void vq_score(const float* __restrict__ z,
                                                   const unsigned short* __restrict__ planes,
                                                   const float* __restrict__ esq,
                                                   float4* __restrict__ pquad) {
    const int tid  = threadIdx.x;
    const int lane = tid & 63;
    const int w    = tid >> 6;
    const int l15  = lane & 15;
    const int l4h  = lane >> 4;
    const int sliceW = blockIdx.x >> 7;
    const int chunk  = blockIdx.x & 127;
    const int sub    = sliceW * 4 + w;
    const int kbase  = sub * 64;

    s16x8 ch[4][4], cl[4][4];
    {
        const unsigned short* gp = planes + (size_t)sub * 16384;
#pragma unroll
        for (int ks = 0; ks < 4; ++ks)
#pragma unroll
            for (int ct = 0; ct < 4; ++ct) {
                const int off = ((((ks * 4 + l4h) << 6) + (ct << 4) + l15) << 3);
                ch[ct][ks] = *reinterpret_cast<const s16x8*>(gp + off);
                cl[ct][ks] = *reinterpret_cast<const s16x8*>(gp + 8192 + off);
            }
    }
    float ekv[16];
#pragma unroll
    for (int ct = 0; ct < 4; ++ct)
#pragma unroll
        for (int e = 0; e < 4; ++e)
            ekv[ct * 4 + e] = esq[kbase + ct * 16 + l4h * 4 + e];

    const int rbase = chunk * 1024;
    float4* pq = pquad + (size_t)sub * BN;

#pragma unroll 1
    for (int t = 0; t < 64; ++t) {
        const int r0 = rbase + t * 16;
        s16x8 zh[4], zl[4];
#pragma unroll
        for (int ks = 0; ks < 4; ++ks) {
            const float* src = z + (size_t)(r0 + l15) * DN + ks * 32 + l4h * 8;
            const float4 v0 = *reinterpret_cast<const float4*>(src);
            const float4 v1 = *reinterpret_cast<const float4*>(src + 4);
            cvt8(v0, v1, zh[ks], zl[ks]);
        }
        tile_compute(ch, cl, zh, zl, ekv, kbase, r0, pq, l15, l4h);
    }
}

// ===========================================================================
// PHASE 2a (merge, R12-validated structure, med3 inserts): 512 x 256, one
// row per thread, NO LDS, NO barriers. 16-way TOP-3 merge; tier-2 inline
// 2-chain exact rescore; tier-3 -> rescue list; sampled canary -> flag.
// ===========================================================================
template <bool HZ>
__global__ __launch_bounds__(256, 2) void vq_merge3(const float* __restrict__ z,
                                                    const float* __restrict__ cb,
                                                    const float* __restrict__ esq,
                                                    const float* __restrict__ zsqArr,
                                                    const float4* __restrict__ pquad,
                                                    int* __restrict__ rmeta,
                                                    int* __restrict__ rlist,
                                                    float* __restrict__ out) {
    const int tid = threadIdx.x;
    const int r   = blockIdx.x * 256 + tid;

    float zsq;
    if constexpr (HZ) {
        zsq = zsqArr[r];
    } else {
        const float* zr = z + (size_t)r * DN;
        float a8[8];
#pragma unroll
        for (int c = 0; c < 32; ++c) {
            const float4 v = *reinterpret_cast<const float4*>(zr + c * 4);
            const int t0 = 4 * (c & 1);
            if (c < 2) {
                a8[t0 + 0] = __fmul_rn(v.x, v.x);
                a8[t0 + 1] = __fmul_rn(v.y, v.y);
                a8[t0 + 2] = __fmul_rn(v.z, v.z);
                a8[t0 + 3] = __fmul_rn(v.w, v.w);
            } else {
                a8[t0 + 0] = __fadd_rn(a8[t0 + 0], __fmul_rn(v.x, v.x));
                a8[t0 + 1] = __fadd_rn(a8[t0 + 1], __fmul_rn(v.y, v.y));
                a8[t0 + 2] = __fadd_rn(a8[t0 + 2], __fmul_rn(v.z, v.z));
                a8[t0 + 3] = __fadd_rn(a8[t0 + 3], __fmul_rn(v.w, v.w));
            }
        }
        zsq = __fadd_rn(
            __fadd_rn(__fadd_rn(a8[0], a8[1]), __fadd_rn(a8[2], a8[3])),
            __fadd_rn(__fadd_rn(a8[4], a8[5]), __fadd_rn(a8[6], a8[7])));
    }

    // ---- 16-way top-3 merge (med3 inserts; values/indices identical to the
    // validated branch code -- see tile_compute comment) --------------------
    float B1 = INFINITY, B2 = INFINITY, B3 = INFINITY;
    int   I1 = 0, I2 = 0;
#pragma unroll
    for (int half = 0; half < 2; ++half) {
        float4 q[8];
#pragma unroll
        for (int s = 0; s < 8; ++s)
            q[s] = pquad[(size_t)(half * 8 + s) * BN + r];
#pragma unroll
        for (int s = 0; s < 8; ++s) {
            const int ii = __float_as_int(q[s].w);
            const int j1 = ii & 0xffff, j2 = ii >> 16;
            // insert q.x (carries index j1)
            {
                const float sc = q[s].x;
                const bool lt1 = sc < B1;
                const bool lt2 = sc < B2;
                const float nB3 = __builtin_amdgcn_fmed3f(sc, B2, B3);
                const float nB2 = __builtin_amdgcn_fmed3f(sc, B1, B2);
                I2 = lt1 ? I1 : (lt2 ? j1 : I2);
                B3 = nB3;
                B2 = nB2;
                B1 = fminf(sc, B1);
                I1 = lt1 ? j1 : I1;
            }
            // insert q.y (carries index j2; q.y >= q.x so only B2/B3 affected)
            {
                const float sc = q[s].y;
                const bool l2 = sc < B2;
                const float nB3 = __builtin_amdgcn_fmed3f(sc, B2, B3);
                I2 = l2 ? j2 : I2;
                B3 = nB3;
                B2 = fminf(sc, B2);
            }
            // q.z can only affect B3
            B3 = fminf(B3, q[s].z);
        }
    }

    int win = I1;
    if (B3 - B1 <= TAMB) {
        // tier 3 (rare): full exact rescan in the rescue kernel
        const int p = atomicAdd(&rmeta[0], 1);
        rlist[p] = r;
    } else if (B2 - B1 <= TAMB) {
        // tier 2: exact rescore of {I1, I2} (validated chain + tie rule)
        const float da = exact_d2_g(z, cb, r, I1, zsq, esq[I1]);
        const float db = exact_d2_g(z, cb, r, I2, zsq, esq[I2]);
        if (da < db) win = I1;
        else if (db < da) win = I2;
        else win = (I1 < I2) ? I1 : I2;
    }
    out[(size_t)BN * DN + 1 + r] = (float)win;

    // sampled canary: one row per wave; gross failure is systematic
    if ((tid & 63) == 0) {
        const float d2x  = exact_d2_g(z, cb, r, I1, zsq, esq[I1]);
        const float pred = __fadd_rn(zsq, B1);
        if (fabsf(pred - d2x) > CANARY) atomicExch(&rmeta[1], 1);
    }
}

// ===========================================================================
// PHASE 2b (rescue v2, COALESCED, R13-validated): one WAVE per flagged row,
// codes k = c*64 + lane against the TRANSPOSED codebook -> consecutive-lane
// consecutive-float reads. Exact sequential fma chain per code; lexicographic
// wave reduce. Canary flag -> rescans ALL rows.
// ===========================================================================
template <bool HZ>
__global__ __launch_bounds__(256, 2) void vq_rescue2(const float* __restrict__ z,
                                                     const float* __restrict__ cbT,
                                                     const float* __restrict__ esq,
                                                     const float* __restrict__ zsqArr,
                                                     const int* __restrict__ rmeta,
                                                     const int* __restrict__ rlist,
                                                     float* __restrict__ out) {
    const int lane = threadIdx.x & 63;
    const int wid  = blockIdx.x * 4 + (threadIdx.x >> 6);
    const int nw   = gridDim.x * 4;
    const int n    = rmeta[0];
    const int flag = rmeta[1];
    const int total = flag ? BN : n;

    for (int ii = wid; ii < total; ii += nw) {
        const int row = flag ? ii : rlist[ii];
        float zsq;
        if constexpr (HZ) {
            zsq = zsqArr[row];
        } else {
            const float* zr0 = z + (size_t)row * DN;
            float a8[8];
#pragma unroll
            for (int c = 0; c < 32; ++c) {
                const float4 v = *reinterpret_cast<const float4*>(zr0 + c * 4);
                const int t0 = 4 * (c & 1);
                if (c < 2) {
                    a8[t0 + 0] = __fmul_rn(v.x, v.x);
                    a8[t0 + 1] = __fmul_rn(v.y, v.y);
                    a8[t0 + 2] = __fmul_rn(v.z, v.z);
                    a8[t0 + 3] = __fmul_rn(v.w, v.w);
                } else {
                    a8[t0 + 0] = __fadd_rn(a8[t0 + 0], __fmul_rn(v.x, v.x));
                    a8[t0 + 1] = __fadd_rn(a8[t0 + 1], __fmul_rn(v.y, v.y));
                    a8[t0 + 2] = __fadd_rn(a8[t0 + 2], __fmul_rn(v.z, v.z));
                    a8[t0 + 3] = __fadd_rn(a8[t0 + 3], __fmul_rn(v.w, v.w));
                }
            }
            zsq = __fadd_rn(
                __fadd_rn(__fadd_rn(a8[0], a8[1]), __fadd_rn(a8[2], a8[3])),
                __fadd_rn(__fadd_rn(a8[4], a8[5]), __fadd_rn(a8[6], a8[7])));
        }

        const float* zr = z + (size_t)row * DN;
        float acc[16];
#pragma unroll
        for (int c = 0; c < 16; ++c) acc[c] = 0.0f;
#pragma unroll 1
        for (int d = 0; d < DN; ++d) {
            const float zd = zr[d];                       // wave-uniform
            const float* cd = cbT + (size_t)d * KN + lane;
#pragma unroll
            for (int c = 0; c < 16; ++c)
                acc[c] = __fmaf_rn(zd, cd[c * 64], acc[c]);
        }
        // in-lane best: codes k = c*64+lane ascend in c; strict < keeps lowest
        float best = INFINITY; int bi = 0;
#pragma unroll
        for (int c = 0; c < 16; ++c) {
            const int k = c * 64 + lane;
            const float d2 = __fadd_rn(__fsub_rn(zsq, __fmul_rn(2.0f, acc[c])),
                                       esq[k]);
            if (d2 < best) { best = d2; bi = k; }
        }
#pragma unroll
        for (int m = 1; m < 64; m <<= 1) {
            const float ob  = __shfl_xor(best, m);
            const int   obi = __shfl_xor(bi, m);
            if (ob < best || (ob == best && obi < bi)) { best = ob; bi = obi; }
        }
        if (lane == 0) out[(size_t)BN * DN + 1 + row] = (float)bi;
    }
}

// ===========================================================================
// PHASE 2c (epilogue): pure streaming (R9/R13-validated). 2048 x 256.
// ===========================================================================
__global__ __launch_bounds__(256, 4) void vq_epilogue(const float* __restrict__ z,
                                                      const float* __restrict__ cb,
                                                      float* __restrict__ out,
                                                      double* __restrict__ partials) {
    __shared__ int sidx[EROWS];
    __shared__ double sls[256];
    const int tid  = threadIdx.x;
    const int row0 = blockIdx.x * EROWS;

    if (tid < EROWS)
        sidx[tid] = (int)out[(size_t)BN * DN + 1 + row0 + tid];
    __syncthreads();

    double ls = 0.0;
    const int j = tid & 31;
#pragma unroll
    for (int half = 0; half < 2; ++half) {
        float4 zb[4], cv[4];
        int rr[4];
#pragma unroll
        for (int u = 0; u < 4; ++u) {
            const int it = half * 4 + u;
            rr[u] = it * 8 + (tid >> 5);
            zb[u] = *reinterpret_cast<const float4*>(
                z + (size_t)(row0 + rr[u]) * DN + j * 4);
            cv[u] = *reinterpret_cast<const float4*>(
                cb + (size_t)sidx[rr[u]] * DN + j * 4);
        }
#pragma unroll
        for (int u = 0; u < 4; ++u) {
            *reinterpret_cast<float4*>(out + (size_t)(row0 + rr[u]) * DN + j * 4) = cv[u];
            const float d0 = __fsub_rn(cv[u].x, zb[u].x);
            const float d1 = __fsub_rn(cv[u].y, zb[u].y);
            const float d2e = __fsub_rn(cv[u].z, zb[u].z);
            const float d3 = __fsub_rn(cv[u].w, zb[u].w);
            ls += (double)__fmul_rn(d0, d0);
            ls += (double)__fmul_rn(d1, d1);
            ls += (double)__fmul_rn(d2e, d2e);
            ls += (double)__fmul_rn(d3, d3);
        }
    }
    sls[tid] = ls;
    __syncthreads();
    for (int s = 128; s > 0; s >>= 1) {
        if (tid < s) sls[tid] += sls[tid + s];
        __syncthreads();
    }
    if (tid == 0) partials[blockIdx.x] = sls[0];
}

#define UPD(s, sc, kk) { \
    const bool lt1 = (sc) < b1v[s]; \
    const bool lt2 = (sc) < b2v[s]; \
    const bool lt3 = (sc) < b3v[s]; \
    b3v[s] = lt2 ? b2v[s] : (lt3 ? (sc) : b3v[s]); \
    b2v[s] = lt1 ? b1v[s] : (lt2 ? (sc) : b2v[s]); \
    i2v[s] = lt1 ? i1v[s] : (lt2 ? (kk) : i2v[s]); \
    b1v[s] = lt1 ? (sc) : b1v[s]; \
    i1v[s] = lt1 ? (kk) : i1v[s]; }

// ---------------------------------------------------------------------------
// Fallback (small workspace): validated R2-structure LDS kernel, in-kernel cvt.
// ---------------------------------------------------------------------------
__global__ __launch_bounds__(256, 2) void vq_lds(const float* __restrict__ z,
                                                 const float* __restrict__ cb,
                                                 const float* __restrict__ esq,
                                                 float* __restrict__ out,
                                                 double* __restrict__ partials) {
    __shared__ __align__(16) short cbS[2][16384];
    __shared__ __align__(16) float sEsq[KN];
    __shared__ float  szsq[ROWS];
    __shared__ float  sB1[2][ROWS], sB2[2][ROWS], sB3[2][ROWS];
    __shared__ int    sI1[2][ROWS], sI2[2][ROWS];
    __shared__ int    sbidx[ROWS];
    __shared__ int    t2list[ROWS], t3list[ROWS];
    __shared__ int    t2n, t3n;
    __shared__ double sls[256];

    const int tid  = threadIdx.x;
    const int lane = tid & 63;
    const int w    = tid >> 6;
    const int l15  = lane & 15;
    const int l4h  = lane >> 4;
    const int wr   = w >> 1;
    const int wc   = w & 1;
    const int row0 = blockIdx.x * ROWS;

    if (tid == 0) { t2n = 0; t3n = 0; }
#pragma unroll
    for (int i = 0; i < 4; ++i) sEsq[i * 256 + tid] = esq[i * 256 + tid];

    float4 stg[8];
#pragma unroll
    for (int i = 0; i < 4; ++i) {
        const int mc = i * 256 + tid, m = mc >> 6, c = mc & 63;
        const float* src = cb + ((size_t)c) * DN + m * 8;
        stg[2 * i]     = *reinterpret_cast<const float4*>(src);
        stg[2 * i + 1] = *reinterpret_cast<const float4*>(src + 4);
    }

    if (tid < ROWS) {
        const float* zr = z + (size_t)(row0 + tid) * DN;
        float rr[8];
#pragma unroll
        for (int c = 0; c < 32; ++c) {
            const float4 v = *reinterpret_cast<const float4*>(zr + c * 4);
            const int t0 = 4 * (c & 1);
            if (c < 2) {
                rr[t0 + 0] = __fmul_rn(v.x, v.x);
                rr[t0 + 1] = __fmul_rn(v.y, v.y);
                rr[t0 + 2] = __fmul_rn(v.z, v.z);
                rr[t0 + 3] = __fmul_rn(v.w, v.w);
            } else {
                rr[t0 + 0] = __fadd_rn(rr[t0 + 0], __fmul_rn(v.x, v.x));
                rr[t0 + 1] = __fadd_rn(rr[t0 + 1], __fmul_rn(v.y, v.y));
                rr[t0 + 2] = __fadd_rn(rr[t0 + 2], __fmul_rn(v.z, v.z));
                rr[t0 + 3] = __fadd_rn(rr[t0 + 3], __fmul_rn(v.w, v.w));
            }
        }
        szsq[tid] = __fadd_rn(
            __fadd_rn(__fadd_rn(rr[0], rr[1]), __fadd_rn(rr[2], rr[3])),
            __fadd_rn(__fadd_rn(rr[4], rr[5]), __fadd_rn(rr[6], rr[7])));
    }

    {
        short* dst = &cbS[0][0];
#pragma unroll
        for (int i = 0; i < 4; ++i) {
            const int mc = i * 256 + tid, m = mc >> 6, c = mc & 63;
            s16x4 h0, l0, h1, l1;
            cvt4(stg[2 * i], h0, l0); cvt4(stg[2 * i + 1], h1, l1);
            short* hb = dst + (m * 64 + c) * 8;
            *reinterpret_cast<s16x4*>(hb)     = h0;
            *reinterpret_cast<s16x4*>(hb + 4) = h1;
            short* lb = hb + 8192;
            *reinterpret_cast<s16x4*>(lb)     = l0;
            *reinterpret_cast<s16x4*>(lb + 4) = l1;
        }
    }

    s16x8 zha[2][4], zla[2][4];
#pragma unroll
    for (int rt = 0; rt < 2; ++rt) {
#pragma unroll
        for (int ks = 0; ks < 4; ++ks) {
            const int rl = row0 + wr * 32 + rt * 16 + l15;
            const float* src = z + (size_t)rl * DN + ks * 32 + l4h * 8;
            const float4 v0 = *reinterpret_cast<const float4*>(src);
            const float4 v1 = *reinterpret_cast<const float4*>(src + 4);
            cvt8(v0, v1, zha[rt][ks], zla[rt][ks]);
        }
    }
    __syncthreads();

    float b1v[8], b2v[8], b3v[8]; int i1v[8], i2v[8];
#pragma unroll
    for (int s = 0; s < 8; ++s) {
        b1v[s] = INFINITY; b2v[s] = INFINITY; b3v[s] = INFINITY;
        i1v[s] = 0; i2v[s] = 0;
    }

    for (int g = 0; g < NGRP; ++g) {
        const int buf = g & 1;
        if (g < NGRP - 1) {
            const int gb = (g + 1) * GCODES;
#pragma unroll
            for (int i = 0; i < 4; ++i) {
                const int mc = i * 256 + tid, m = mc >> 6, c = mc & 63;
                const float* src = cb + ((size_t)(gb + c)) * DN + m * 8;
                stg[2 * i]     = *reinterpret_cast<const float4*>(src);
                stg[2 * i + 1] = *reinterpret_cast<const float4*>(src + 4);
            }
        }

        f32x4 acc[2][2];
#pragma unroll
        for (int rt = 0; rt < 2; ++rt)
#pragma unroll
            for (int ct = 0; ct < 2; ++ct)
                acc[rt][ct] = (f32x4){0.0f, 0.0f, 0.0f, 0.0f};

#pragma unroll
        for (int ks = 0; ks < 4; ++ks) {
            const int b0 = (((ks * 4 + l4h) << 6) + (wc << 5) + l15) << 3;
            const s16x8 bh0 = *reinterpret_cast<const s16x8*>(&cbS[buf][b0]);
            const s16x8 bl0 = *reinterpret_cast<const s16x8*>(&cbS[buf][8192 + b0]);
            const s16x8 bh1 = *reinterpret_cast<const s16x8*>(&cbS[buf][b0 + 128]);
            const s16x8 bl1 = *reinterpret_cast<const s16x8*>(&cbS[buf][8192 + b0 + 128]);
            acc[0][0] = __builtin_amdgcn_mfma_f32_16x16x32_bf16(zha[0][ks], bh0, acc[0][0], 0, 0, 0);
            acc[0][0] = __builtin_amdgcn_mfma_f32_16x16x32_bf16(zla[0][ks], bh0, acc[0][0], 0, 0, 0);
            acc[0][0] = __builtin_amdgcn_mfma_f32_16x16x32_bf16(zha[0][ks], bl0, acc[0][0], 0, 0, 0);
            acc[1][0] = __builtin_amdgcn_mfma_f32_16x16x32_bf16(zha[1][ks], bh0, acc[1][0], 0, 0, 0);
            acc[1][0] = __builtin_amdgcn_mfma_f32_16x16x32_bf16(zla[1][ks], bh0, acc[1][0], 0, 0, 0);
            acc[1][0] = __builtin_amdgcn_mfma_f32_16x16x32_bf16(zha[1][ks], bl0, acc[1][0], 0, 0, 0);
            acc[0][1] = __builtin_amdgcn_mfma_f32_16x16x32_bf16(zha[0][ks], bh1, acc[0][1], 0, 0, 0);
            acc[0][1] = __builtin_amdgcn_mfma_f32_16x16x32_bf16(zla[0][ks], bh1, acc[0][1], 0, 0, 0);
            acc[0][1] = __builtin_amdgcn_mfma_f32_16x16x32_bf16(zha[0][ks], bl1, acc[0][1], 0, 0, 0);
            acc[1][1] = __builtin_amdgcn_mfma_f32_16x16x32_bf16(zha[1][ks], bh1, acc[1][1], 0, 0, 0);
            acc[1][1] = __builtin_amdgcn_mfma_f32_16x16x32_bf16(zla[1][ks], bh1, acc[1][1], 0, 0, 0);
            acc[1][1] = __builtin_amdgcn_mfma_f32_16x16x32_bf16(zha[1][ks], bl1, acc[1][1], 0, 0, 0);
        }

#pragma unroll
        for (int ct = 0; ct < 2; ++ct) {
            const int k = g * GCODES + wc * 32 + ct * 16 + l15;
            const float ek = sEsq[k];
#pragma unroll
            for (int rt = 0; rt < 2; ++rt) {
#pragma unroll
                for (int e = 0; e < 4; ++e) {
                    const float sc = __fmaf_rn(-2.0f, acc[rt][ct][e], ek);
                    UPD(rt * 4 + e, sc, k)
                }
            }
        }

        if (g < NGRP - 1) {
            short* dst = &cbS[buf ^ 1][0];
#pragma unroll
            for (int i = 0; i < 4; ++i) {
                const int mc = i * 256 + tid, m = mc >> 6, c = mc & 63;
                s16x4 h0, l0, h1, l1;
                cvt4(stg[2 * i], h0, l0); cvt4(stg[2 * i + 1], h1, l1);
                short* hb = dst + (m * 64 + c) * 8;
                *reinterpret_cast<s16x4*>(hb)     = h0;
                *reinterpret_cast<s16x4*>(hb + 4) = h1;
                short* lb = hb + 8192;
                *reinterpret_cast<s16x4*>(lb)     = l0;
                *reinterpret_cast<s16x4*>(lb + 4) = l1;
            }
        }
        __syncthreads();
    }

#pragma unroll
    for (int st = 1; st < 16; st <<= 1) {
#pragma unroll
        for (int s = 0; s < 8; ++s) {
            const float ob1 = __shfl_xor(b1v[s], st);
            const int   oi1 = __shfl_xor(i1v[s], st);
            const float ob2 = __shfl_xor(b2v[s], st);
            const int   oi2 = __shfl_xor(i2v[s], st);
            const float ob3 = __shfl_xor(b3v[s], st);
            float v1, v2, v3; int j1, j2;
            if (ob1 < b1v[s]) {
                v1 = ob1; j1 = oi1;
                if (b1v[s] < ob2) { v2 = b1v[s]; j2 = i1v[s]; v3 = fminf(b2v[s], ob2); }
                else              { v2 = ob2;    j2 = oi2;    v3 = fminf(b1v[s], ob3); }
            } else {
                v1 = b1v[s]; j1 = i1v[s];
                if (ob1 < b2v[s]) { v2 = ob1;    j2 = oi1;    v3 = fminf(ob2, b2v[s]); }
                else              { v2 = b2v[s]; j2 = i2v[s]; v3 = fminf(ob1, b3v[s]); }
            }
            b1v[s] = v1; i1v[s] = j1; b2v[s] = v2; i2v[s] = j2; b3v[s] = v3;
        }
    }
    if (l15 == 0) {
#pragma unroll
        for (int s = 0; s < 8; ++s) {
            const int r = wr * 32 + (s >> 2) * 16 + l4h * 4 + (s & 3);
            sB1[wc][r] = b1v[s]; sI1[wc][r] = i1v[s];
            sB2[wc][r] = b2v[s]; sI2[wc][r] = i2v[s];
            sB3[wc][r] = b3v[s];
        }
    }
    __syncthreads();

    if (tid < ROWS) {
        const float a1 = sB1[0][tid]; const int aj1 = sI1[0][tid];
        const float a2 = sB2[0][tid]; const int aj2 = sI2[0][tid];
        const float a3 = sB3[0][tid];
        const float c1 = sB1[1][tid]; const int cj1 = sI1[1][tid];
        const float c2 = sB2[1][tid]; const int cj2 = sI2[1][tid];
        const float c3 = sB3[1][tid];
        float b1, b2, b3; int i1, i2;
        if (a1 <= c1) {
            b1 = a1; i1 = aj1;
            if (a2 <= c1) { b2 = a2; i2 = aj2; b3 = fminf(a3, c1); }
            else          { b2 = c1; i2 = cj1; b3 = fminf(a2, c2); }
        } else {
            b1 = c1; i1 = cj1;
            if (c2 <= a1) { b2 = c2; i2 = cj2; b3 = fminf(c3, a1); }
            else          { b2 = a1; i2 = aj1; b3 = fminf(c2, a2); }
        }
        sbidx[tid] = i1;
        sI1[0][tid] = i1; sI2[0][tid] = i2;
        const float d2x  = exact_d2_g(z, cb, row0 + tid, i1, szsq[tid], sEsq[i1]);
        const float pred = __fadd_rn(szsq[tid], b1);
        const bool bad   = fabsf(pred - d2x) > CANARY;
        if (bad || (b3 - b1 <= TAMB)) {
            const int p = atomicAdd(&t3n, 1); t3list[p] = tid;
        } else if (b2 - b1 <= TAMB) {
            const int p = atomicAdd(&t2n, 1); t2list[p] = tid;
        }
    }
    __syncthreads();

    if (tid < t2n) {
        const int r  = t2list[tid];
        const int ka = sI1[0][r], kb = sI2[0][r];
        const float zsq = szsq[r];
        const float da = exact_d2_g(z, cb, row0 + r, ka, zsq, sEsq[ka]);
        const float db = exact_d2_g(z, cb, row0 + r, kb, zsq, sEsq[kb]);
        int win;
        if (da < db) win = ka;
        else if (db < da) win = kb;
        else win = (ka < kb) ? ka : kb;
        sbidx[r] = win;
    }
    for (int ii = w; ii < t3n; ii += 4) {
        const int r = t3list[ii];
        const float zsq = szsq[r];
        float best = INFINITY; int bi = 0;
#pragma unroll 1
        for (int kk = 0; kk < 16; ++kk) {
            const int k = lane * 16 + kk;
            const float d2v = exact_d2_g(z, cb, row0 + r, k, zsq, sEsq[k]);
            if (d2v < best) { best = d2v; bi = k; }
        }
#pragma unroll
        for (int m = 1; m < 64; m <<= 1) {
            const float ob  = __shfl_xor(best, m);
            const int   obi = __shfl_xor(bi, m);
            if (ob < best || (ob == best && obi < bi)) { best = ob; bi = obi; }
        }
        if (lane == 0) sbidx[r] = bi;
    }
    __syncthreads();

    if (tid < ROWS)
        out[(size_t)BN * DN + 1 + row0 + tid] = (float)sbidx[tid];

    double ls = 0.0;
#pragma unroll
    for (int it = 0; it < 8; ++it) {
        const int r = it * 8 + (tid >> 5);
        const int j = tid & 31;
        const float4 zv = *reinterpret_cast<const float4*>(
            z + ((size_t)(row0 + r)) * DN + j * 4);
        const int bfin = sbidx[r];
        const float4 cv = *reinterpret_cast<const float4*>(
            cb + ((size_t)bfin) * DN + j * 4);
        *reinterpret_cast<float4*>(out + ((size_t)(row0 + r)) * DN + j * 4) = cv;
        const float d0 = __fsub_rn(cv.x, zv.x);
        const float d1 = __fsub_rn(cv.y, zv.y);
        const float d2e = __fsub_rn(cv.z, zv.z);
        const float d3 = __fsub_rn(cv.w, zv.w);
        ls += (double)__fmul_rn(d0, d0);
        ls += (double)__fmul_rn(d1, d1);
        ls += (double)__fmul_rn(d2e, d2e);
        ls += (double)__fmul_rn(d3, d3);
    }
    sls[tid] = ls;
    __syncthreads();
    for (int s = 128; s > 0; s >>= 1) {
        if (tid < s) sls[tid] += sls[tid + s];
        __syncthreads();
    }
    if (tid == 0) partials[blockIdx.x] = sls[0];
}

// ---------------------------------------------------------------------------
// Final loss reduction over n block partials (deterministic)
// ---------------------------------------------------------------------------
__global__ __launch_bounds__(256) void loss_kernel(const double* __restrict__ partials,
                                                   float* __restrict__ out, int n) {
    __shared__ double s[256];
    double acc = 0.0;
    for (int i = threadIdx.x; i < n; i += 256) acc += partials[i];
    s[threadIdx.x] = acc;
    __syncthreads();
    for (int t = 128; t > 0; t >>= 1) {
        if (threadIdx.x < t) s[threadIdx.x] += s[threadIdx.x + t];
        __syncthreads();
    }
    if (threadIdx.x == 0)
        out[(size_t)BN * DN] = (float)(s[0] / ((double)BN * (double)DN));
}

extern "C" void kernel_launch(void* const* d_in, const int* in_sizes, int n_in,
                              void* d_out, int out_size, void* d_ws, size_t ws_size,
                              hipStream_t stream) {
    const float* z  = (const float*)d_in[0];
    const float* cb = (const float*)d_in[1];
    float* out = (float*)d_out;

    // Workspace layout:
    //   [0, 4096)                esq
    //   [4096, 20480)            2048 double partials
    //   [20480, 544768)          cb planes (512KB)
    //   [544768, 34099200)       pquad: 16 x BN x float4 (32MB)
    //   [34099200, 34099328)     rmeta: rcount, gflag
    //   [34099328, 34623616)     rlist (512KB)
    //   [34623616, 35147904)     cbT fp32 transposed (512KB) == need_mid
    //   [35147904, 35672192)     zsq (512KB)
    //   [35672192, 102781056)    z planes (64MB)             == need_full
    float*          esq      = (float*)d_ws;
    double*         partials = (double*)((char*)d_ws + 4096);
    unsigned short* cbpl     = (unsigned short*)((char*)d_ws + 20480);
    float4*         pquad    = (float4*)((char*)d_ws + 544768);
    int*            rmeta    = (int*)((char*)d_ws + 34099200ull);
    int*            rlist    = (int*)((char*)d_ws + 34099328ull);
    float*          cbT      = (float*)((char*)d_ws + 34623616ull);
    float*          zsqArr   = (float*)((char*)d_ws + 35147904ull);
    unsigned short* zpl      = (unsigned short*)((char*)d_ws + 35672192ull);
    const size_t need_mid  = 35147904ull;
    const size_t need_full = 102781056ull;

    esq_kernel<<<KN / 256, 256, 0, stream>>>(cb, esq);
    if (ws_size >= need_full) {
        cvt_kernel  <<<64, 256, 0, stream>>>(cb, cbpl);
        cvtT_kernel <<<512, 256, 0, stream>>>(cb, cbT);
        zprep_kernel<<<BN / 256, 256, 0, stream>>>(z, zpl, zsqArr);
        vq_score_pre<<<1024, 256, 0, stream>>>(zpl, cbpl, esq, pquad);
        hipMemsetAsync(rmeta, 0, 8, stream);
        vq_merge3<true>  <<<512, 256, 0, stream>>>(z, cb, esq, zsqArr, pquad, rmeta, rlist, out);
        vq_rescue2<true> <<<512, 256, 0, stream>>>(z, cbT, esq, zsqArr, rmeta, rlist, out);
        vq_epilogue <<<EBLK, 256, 0, stream>>>(z, cb, out, partials);
        loss_kernel <<<1, 256, 0, stream>>>(partials, out, EBLK);
    } else if (ws_size >= need_mid) {
        cvt_kernel <<<64, 256, 0, stream>>>(cb, cbpl);
        cvtT_kernel<<<512, 256, 0, stream>>>(cb, cbT);
        vq_score   <<<512, 256, 0, stream>>>(z, cbpl, esq, pquad);
        hipMemsetAsync(rmeta, 0, 8, stream);
        vq_merge3<false>  <<<512, 256, 0, stream>>>(z, cb, esq, nullptr, pquad, rmeta, rlist, out);
        vq_rescue2<false> <<<512, 256, 0, stream>>>(z, cbT, esq, nullptr, rmeta, rlist, out);
        vq_epilogue<<<EBLK, 256, 0, stream>>>(z, cb, out, partials);
        loss_kernel<<<1, 256, 0, stream>>>(partials, out, EBLK);
    } else {
        vq_lds<<<NBLK, 256, 0, stream>>>(z, cb, esq, out, partials);
        loss_kernel<<<1, 256, 0, stream>>>(partials, out, NBLK);
    }
}